// Round 9
// baseline (494.668 us; speedup 1.0000x reference)
//
#include <hip/hip_runtime.h>
#include <hip/hip_bf16.h>
#include <hip/hip_fp16.h>

// GCN, dis-folded: A_norm = D^-1/2 (A_w + I) D^-1/2; CSR stores raw w.
// R9: hidden features in f16 (RNE), quarter-wave uint4 gathers (4 edges/wave-instr),
//     packed __hfma2 accumulation (v_pk_fma_f16) -> ~2.5 instr/edge vs 6.5.
//     R8 postmortem: bf16 unpack made props issue-bound (VALU 46%).

#define FEAT 128
#define BSH 8                 // bucket shift
#define BCAP 8192             // entries per bucket (mean 4092)

typedef union { int2 i2; long long u; struct { int s; float w; } e; } EdgePair;
typedef union { unsigned u; __half2 h2; } H2U;

__device__ __forceinline__ unsigned pack2h(float a, float b) {
    return (unsigned)__half_as_ushort(__float2half_rn(a)) |
           ((unsigned)__half_as_ushort(__float2half_rn(b)) << 16);   // RNE both
}

// ---------------- pass 1: bin edges by dst>>8 ----------------
__global__ __launch_bounds__(256) void bin1_kernel(const int* __restrict__ src,
                                                   const int* __restrict__ dst,
                                                   const float* __restrict__ w,
                                                   int* __restrict__ gcnt,
                                                   int2* __restrict__ bins,
                                                   int E_, int NB) {
    __shared__ int lh[392], lbase[392], lcur[392];
    const int CHUNK = 4096;
    int base = blockIdx.x * CHUNK;
    for (int t = threadIdx.x; t < NB; t += 256) { lh[t] = 0; lcur[t] = 0; }
    __syncthreads();
    int ds[16];
#pragma unroll
    for (int j = 0; j < 16; ++j) {
        int e = base + j * 256 + threadIdx.x;
        ds[j] = (e < E_) ? dst[e] : -1;
        if (ds[j] >= 0) atomicAdd(&lh[ds[j] >> BSH], 1);
    }
    __syncthreads();
    for (int t = threadIdx.x; t < NB; t += 256)
        if (lh[t] > 0) lbase[t] = atomicAdd(&gcnt[t], lh[t]);
    __syncthreads();
#pragma unroll
    for (int j = 0; j < 16; ++j) {
        int e = base + j * 256 + threadIdx.x;
        if (ds[j] >= 0) {
            int b = ds[j] >> BSH;
            int idx = lbase[b] + atomicAdd(&lcur[b], 1);
            if (idx < BCAP) {
                EdgePair p;
                p.e.s = src[e] | ((ds[j] & 255) << 20);
                p.e.w = w[e];
                bins[(size_t)b * BCAP + idx] = p.i2;
            }
        }
    }
}

// ---------------- pass 2a: per-node counts from bins ----------------
__global__ __launch_bounds__(256) void cnt2_kernel(const int2* __restrict__ bins,
                                                   const int* __restrict__ gcnt,
                                                   int* __restrict__ cnt, int n) {
    __shared__ int lh[256];
    int b = blockIdx.x;
    lh[threadIdx.x] = 0;
    __syncthreads();
    int m = min(gcnt[b], BCAP);
    const int2* bp = bins + (size_t)b * BCAP;
    for (int i = threadIdx.x; i < m; i += 256) {
        unsigned p = (unsigned)bp[i].x;
        atomicAdd(&lh[p >> 20], 1);
    }
    __syncthreads();
    int node = (b << BSH) + threadIdx.x;
    if (node < n) cnt[node] = lh[threadIdx.x] + 1;   // +1 self-loop
}

// ---------------- exclusive scan (compact, 3-phase, chunk=1024) ----------------
__global__ __launch_bounds__(256) void scan_blk(const int* __restrict__ in, int* __restrict__ out,
                                                int* __restrict__ bsum, int n) {
    __shared__ int sd[256];
    int tid = threadIdx.x;
    int base = blockIdx.x * 1024 + tid * 4;
    int v[4];
#pragma unroll
    for (int i = 0; i < 4; ++i) v[i] = (base + i < n) ? in[base + i] : 0;
    int tot = v[0] + v[1] + v[2] + v[3];
    sd[tid] = tot; __syncthreads();
    for (int off = 1; off < 256; off <<= 1) {
        int x = (tid >= off) ? sd[tid - off] : 0;
        __syncthreads();
        sd[tid] += x;
        __syncthreads();
    }
    int excl = sd[tid] - tot;
    if (tid == 255) bsum[blockIdx.x] = sd[255];
    int run = excl;
#pragma unroll
    for (int i = 0; i < 4; ++i) { if (base + i < n) out[base + i] = run; run += v[i]; }
}

__global__ __launch_bounds__(256) void scan_top(int* __restrict__ bsum, int nb) {
    __shared__ int sd[256];
    int tid = threadIdx.x;
    int v[4];
#pragma unroll
    for (int i = 0; i < 4; ++i) {
        int idx = tid * 4 + i;
        v[i] = (idx < nb) ? bsum[idx] : 0;
    }
    int tot = v[0] + v[1] + v[2] + v[3];
    sd[tid] = tot; __syncthreads();
    for (int off = 1; off < 256; off <<= 1) {
        int x = (tid >= off) ? sd[tid - off] : 0;
        __syncthreads();
        sd[tid] += x;
        __syncthreads();
    }
    int excl = sd[tid] - tot;
    int run = excl;
#pragma unroll
    for (int i = 0; i < 4; ++i) {
        int idx = tid * 4 + i;
        if (idx < nb) bsum[idx] = run;
        run += v[i];
    }
}

__global__ void scan_add(int* __restrict__ rp, const int* __restrict__ bsum, int n, int total) {
    int idx = blockIdx.x * blockDim.x + threadIdx.x;
    if (idx < n) rp[idx] += bsum[idx >> 10];
    if (idx == 0) rp[n] = total;
}

// ---------------- pass 2b: drain buckets -> cv; fused per-node deg -> dis ----------------
__global__ __launch_bounds__(256) void scat2_kernel(const int2* __restrict__ bins,
                                                    const int* __restrict__ gcnt,
                                                    const int* __restrict__ rp,
                                                    int2* __restrict__ cv,
                                                    float* __restrict__ dis, int n) {
    __shared__ int lcur[256];
    __shared__ float wsum[256];
    int b = blockIdx.x;
    int node0 = b << BSH;
    int node = node0 + threadIdx.x;
    lcur[threadIdx.x] = (node < n) ? rp[node] : 0;
    wsum[threadIdx.x] = 1.0f;   // self-loop weight
    __syncthreads();
    int m = min(gcnt[b], BCAP);
    const int2* bp = bins + (size_t)b * BCAP;
    for (int i = threadIdx.x; i < m; i += 256) {
        int2 raw = bp[i];
        unsigned pk = (unsigned)raw.x;
        int dlo = pk >> 20;
        int pos = atomicAdd(&lcur[dlo], 1);
        atomicAdd(&wsum[dlo], __int_as_float(raw.y));
        EdgePair q; q.e.s = (int)(pk & 0xFFFFF); q.i2.y = raw.y;
        cv[pos] = q.i2;
    }
    __syncthreads();
    if (node < n) {                       // self-loop entry, w = 1
        int pos = atomicAdd(&lcur[threadIdx.x], 1);
        EdgePair q; q.e.s = node; q.e.w = 1.0f;
        cv[pos] = q.i2;
        dis[node] = rsqrtf(fmaxf(wsum[threadIdx.x], 1e-12f));
    }
}

// ---------------- GEMM1: C_f16[M x 128] = rowscale .* (A_f32 @ B) ----------------
__global__ __launch_bounds__(256) void gemm_f32in(const float* __restrict__ A,
                                                  const float* __restrict__ B,
                                                  const float* __restrict__ rowscale,
                                                  unsigned short* __restrict__ C, int M) {
    __shared__ float As[32][64];
    __shared__ float Bs[32][128];
    int tid = threadIdx.x;
    int row0 = blockIdx.x * 64;
    int tx = tid & 15;
    int ty = tid >> 4;
    float acc[4][8] = {};
    int a_r = tid >> 3;
    int a_c = (tid & 7) << 2;
    int b_r = tid >> 5;
    int b_c = (tid & 31) << 2;
    for (int k0 = 0; k0 < 128; k0 += 32) {
#pragma unroll
        for (int i = 0; i < 2; ++i) {
            int r = a_r + i * 32;
            int gr = row0 + r;
            float4 v = (gr < M) ? *(const float4*)&A[(size_t)gr * 128 + k0 + a_c]
                                : make_float4(0.f, 0.f, 0.f, 0.f);
            As[a_c + 0][r] = v.x; As[a_c + 1][r] = v.y;
            As[a_c + 2][r] = v.z; As[a_c + 3][r] = v.w;
        }
#pragma unroll
        for (int i = 0; i < 4; ++i) {
            int r = b_r + i * 8;
            *(float4*)&Bs[r][b_c] = *(const float4*)&B[(size_t)(k0 + r) * 128 + b_c];
        }
        __syncthreads();
#pragma unroll
        for (int k = 0; k < 32; ++k) {
            float4 a  = *(const float4*)&As[k][ty * 4];
            float4 bv0 = *(const float4*)&Bs[k][tx * 8];
            float4 bv1 = *(const float4*)&Bs[k][tx * 8 + 4];
            float av[4] = {a.x, a.y, a.z, a.w};
            float bv[8] = {bv0.x, bv0.y, bv0.z, bv0.w, bv1.x, bv1.y, bv1.z, bv1.w};
#pragma unroll
            for (int i = 0; i < 4; ++i)
#pragma unroll
                for (int j = 0; j < 8; ++j)
                    acc[i][j] = fmaf(av[i], bv[j], acc[i][j]);
        }
        __syncthreads();
    }
#pragma unroll
    for (int i = 0; i < 4; ++i) {
        int gr = row0 + ty * 4 + i;
        if (gr < M) {
            float sc = rowscale[gr];
            uint4 pk;
            pk.x = pack2h(sc * acc[i][0], sc * acc[i][1]);
            pk.y = pack2h(sc * acc[i][2], sc * acc[i][3]);
            pk.z = pack2h(sc * acc[i][4], sc * acc[i][5]);
            pk.w = pack2h(sc * acc[i][6], sc * acc[i][7]);
            *(uint4*)&C[(size_t)gr * 128 + tx * 8] = pk;
        }
    }
}

// ---------------- GEMM2: C_f16[M x 128] = rowscale .* (A_f16 @ B) ----------------
__global__ __launch_bounds__(256) void gemm_f16in(const unsigned short* __restrict__ A,
                                                  const float* __restrict__ B,
                                                  const float* __restrict__ rowscale,
                                                  unsigned short* __restrict__ C, int M) {
    __shared__ float As[32][64];
    __shared__ float Bs[32][128];
    int tid = threadIdx.x;
    int row0 = blockIdx.x * 64;
    int tx = tid & 15;
    int ty = tid >> 4;
    float acc[4][8] = {};
    int a_r = tid >> 3;
    int a_c = (tid & 7) << 2;
    int b_r = tid >> 5;
    int b_c = (tid & 31) << 2;
    for (int k0 = 0; k0 < 128; k0 += 32) {
#pragma unroll
        for (int i = 0; i < 2; ++i) {
            int r = a_r + i * 32;
            int gr = row0 + r;
            uint2 v = (gr < M) ? *(const uint2*)&A[(size_t)gr * 128 + k0 + a_c]
                               : make_uint2(0u, 0u);
            H2U u0, u1; u0.u = v.x; u1.u = v.y;
            float2 f0 = __half22float2(u0.h2);
            float2 f1 = __half22float2(u1.h2);
            As[a_c + 0][r] = f0.x; As[a_c + 1][r] = f0.y;
            As[a_c + 2][r] = f1.x; As[a_c + 3][r] = f1.y;
        }
#pragma unroll
        for (int i = 0; i < 4; ++i) {
            int r = b_r + i * 8;
            *(float4*)&Bs[r][b_c] = *(const float4*)&B[(size_t)(k0 + r) * 128 + b_c];
        }
        __syncthreads();
#pragma unroll
        for (int k = 0; k < 32; ++k) {
            float4 a  = *(const float4*)&As[k][ty * 4];
            float4 bv0 = *(const float4*)&Bs[k][tx * 8];
            float4 bv1 = *(const float4*)&Bs[k][tx * 8 + 4];
            float av[4] = {a.x, a.y, a.z, a.w};
            float bv[8] = {bv0.x, bv0.y, bv0.z, bv0.w, bv1.x, bv1.y, bv1.z, bv1.w};
#pragma unroll
            for (int i = 0; i < 4; ++i)
#pragma unroll
                for (int j = 0; j < 8; ++j)
                    acc[i][j] = fmaf(av[i], bv[j], acc[i][j]);
        }
        __syncthreads();
    }
#pragma unroll
    for (int i = 0; i < 4; ++i) {
        int gr = row0 + ty * 4 + i;
        if (gr < M) {
            float sc = rowscale[gr];
            uint4 pk;
            pk.x = pack2h(sc * acc[i][0], sc * acc[i][1]);
            pk.y = pack2h(sc * acc[i][2], sc * acc[i][3]);
            pk.z = pack2h(sc * acc[i][4], sc * acc[i][5]);
            pk.w = pack2h(sc * acc[i][6], sc * acc[i][7]);
            *(uint4*)&C[(size_t)gr * 128 + tx * 8] = pk;
        }
    }
}

// ---------------- CSR propagate, 128 f16 feats (layer 1) ----------------
// wave/node; quarter-wave: 16 lanes x 8 f16 per edge, 4 edges per wave-instr;
// 16-edge unroll (4 uint4 gathers in flight per lane); packed f16 FMA accumulate.
__global__ __launch_bounds__(256) void prop_kernel(const int* __restrict__ rp,
                                                   const int2* __restrict__ cv,
                                                   const float* __restrict__ dis,
                                                   const unsigned short* __restrict__ t,
                                                   const float* __restrict__ bias,
                                                   unsigned short* __restrict__ out, int n) {
    const long long* cvu = (const long long*)cv;
    int wv = (blockIdx.x * blockDim.x + threadIdx.x) >> 6;
    int lane = threadIdx.x & 63;
    if (wv >= n) return;
    int qtr = lane >> 4, l4 = lane & 15;
    int beg = rp[wv], end = rp[wv + 1];
    __half2 zh = __float2half2_rn(0.f);
    __half2 acc[4][4];
#pragma unroll
    for (int j = 0; j < 4; ++j) { acc[j][0] = zh; acc[j][1] = zh; acc[j][2] = zh; acc[j][3] = zh; }
    int p = beg;
    for (; p + 16 <= end; p += 16) {
        EdgePair q[4];
#pragma unroll
        for (int j = 0; j < 4; ++j) q[j].u = __builtin_nontemporal_load(&cvu[p + 4 * j + qtr]);
        uint4 tv[4];
#pragma unroll
        for (int j = 0; j < 4; ++j) tv[j] = *(const uint4*)&t[(size_t)q[j].e.s * FEAT + 8 * l4];
#pragma unroll
        for (int j = 0; j < 4; ++j) {
            __half2 ww = __float2half2_rn(q[j].e.w);
            H2U a0, a1, a2, a3; a0.u = tv[j].x; a1.u = tv[j].y; a2.u = tv[j].z; a3.u = tv[j].w;
            acc[j][0] = __hfma2(a0.h2, ww, acc[j][0]);
            acc[j][1] = __hfma2(a1.h2, ww, acc[j][1]);
            acc[j][2] = __hfma2(a2.h2, ww, acc[j][2]);
            acc[j][3] = __hfma2(a3.h2, ww, acc[j][3]);
        }
    }
    for (; p + 4 <= end; p += 4) {
        EdgePair q; q.u = __builtin_nontemporal_load(&cvu[p + qtr]);
        uint4 tv = *(const uint4*)&t[(size_t)q.e.s * FEAT + 8 * l4];
        __half2 ww = __float2half2_rn(q.e.w);
        H2U a0, a1, a2, a3; a0.u = tv.x; a1.u = tv.y; a2.u = tv.z; a3.u = tv.w;
        acc[0][0] = __hfma2(a0.h2, ww, acc[0][0]);
        acc[0][1] = __hfma2(a1.h2, ww, acc[0][1]);
        acc[0][2] = __hfma2(a2.h2, ww, acc[0][2]);
        acc[0][3] = __hfma2(a3.h2, ww, acc[0][3]);
    }
    if (p < end) {
        int idx = p + qtr;
        int cl = (idx < end) ? idx : end - 1;
        EdgePair q; q.u = __builtin_nontemporal_load(&cvu[cl]);
        float wq = (idx < end) ? q.e.w : 0.f;
        uint4 tv = *(const uint4*)&t[(size_t)q.e.s * FEAT + 8 * l4];
        __half2 ww = __float2half2_rn(wq);
        H2U a0, a1, a2, a3; a0.u = tv.x; a1.u = tv.y; a2.u = tv.z; a3.u = tv.w;
        acc[1][0] = __hfma2(a0.h2, ww, acc[1][0]);
        acc[1][1] = __hfma2(a1.h2, ww, acc[1][1]);
        acc[1][2] = __hfma2(a2.h2, ww, acc[1][2]);
        acc[1][3] = __hfma2(a3.h2, ww, acc[1][3]);
    }
    float2 s[4];
#pragma unroll
    for (int k = 0; k < 4; ++k) {
        float2 f0 = __half22float2(acc[0][k]);
        float2 f1 = __half22float2(acc[1][k]);
        float2 f2 = __half22float2(acc[2][k]);
        float2 f3 = __half22float2(acc[3][k]);
        s[k].x = (f0.x + f1.x) + (f2.x + f3.x);
        s[k].y = (f0.y + f1.y) + (f2.y + f3.y);
        s[k].x += __shfl_xor(s[k].x, 16, 64);
        s[k].y += __shfl_xor(s[k].y, 16, 64);
        s[k].x += __shfl_xor(s[k].x, 32, 64);
        s[k].y += __shfl_xor(s[k].y, 32, 64);
    }
    if (qtr == 0) {
        float dd = dis[wv];
        float4 b0 = *(const float4*)&bias[8 * l4];
        float4 b1 = *(const float4*)&bias[8 * l4 + 4];
        float r0 = fmaxf(fmaf(dd, s[0].x, b0.x), 0.f);
        float r1 = fmaxf(fmaf(dd, s[0].y, b0.y), 0.f);
        float r2 = fmaxf(fmaf(dd, s[1].x, b0.z), 0.f);
        float r3 = fmaxf(fmaf(dd, s[1].y, b0.w), 0.f);
        float r4 = fmaxf(fmaf(dd, s[2].x, b1.x), 0.f);
        float r5 = fmaxf(fmaf(dd, s[2].y, b1.y), 0.f);
        float r6 = fmaxf(fmaf(dd, s[3].x, b1.z), 0.f);
        float r7 = fmaxf(fmaf(dd, s[3].y, b1.w), 0.f);
        uint4 pk;
        pk.x = pack2h(r0, r1); pk.y = pack2h(r2, r3);
        pk.z = pack2h(r4, r5); pk.w = pack2h(r6, r7);
        *(uint4*)&out[(size_t)wv * FEAT + 8 * l4] = pk;
    }
}

// ---------------- layer-2 prop fused with head projection (f16 t) ----------------
// z[i] = dis[i] * (relu(dis[i]*((A+I)@t)[i] + b1) @ Wc)
__global__ __launch_bounds__(256) void prop_zk_kernel(const int* __restrict__ rp,
                                                      const int2* __restrict__ cv,
                                                      const float* __restrict__ dis,
                                                      const unsigned short* __restrict__ t,
                                                      const float* __restrict__ bias,
                                                      const float* __restrict__ Wc,
                                                      float* __restrict__ z, int n) {
    const long long* cvu = (const long long*)cv;
    int wv = (blockIdx.x * blockDim.x + threadIdx.x) >> 6;
    int lane = threadIdx.x & 63;
    if (wv >= n) return;
    int qtr = lane >> 4, l4 = lane & 15;
    int beg = rp[wv], end = rp[wv + 1];
    __half2 zh = __float2half2_rn(0.f);
    __half2 acc[4][4];
#pragma unroll
    for (int j = 0; j < 4; ++j) { acc[j][0] = zh; acc[j][1] = zh; acc[j][2] = zh; acc[j][3] = zh; }
    int p = beg;
    for (; p + 16 <= end; p += 16) {
        EdgePair q[4];
#pragma unroll
        for (int j = 0; j < 4; ++j) q[j].u = __builtin_nontemporal_load(&cvu[p + 4 * j + qtr]);
        uint4 tv[4];
#pragma unroll
        for (int j = 0; j < 4; ++j) tv[j] = *(const uint4*)&t[(size_t)q[j].e.s * FEAT + 8 * l4];
#pragma unroll
        for (int j = 0; j < 4; ++j) {
            __half2 ww = __float2half2_rn(q[j].e.w);
            H2U a0, a1, a2, a3; a0.u = tv[j].x; a1.u = tv[j].y; a2.u = tv[j].z; a3.u = tv[j].w;
            acc[j][0] = __hfma2(a0.h2, ww, acc[j][0]);
            acc[j][1] = __hfma2(a1.h2, ww, acc[j][1]);
            acc[j][2] = __hfma2(a2.h2, ww, acc[j][2]);
            acc[j][3] = __hfma2(a3.h2, ww, acc[j][3]);
        }
    }
    for (; p + 4 <= end; p += 4) {
        EdgePair q; q.u = __builtin_nontemporal_load(&cvu[p + qtr]);
        uint4 tv = *(const uint4*)&t[(size_t)q.e.s * FEAT + 8 * l4];
        __half2 ww = __float2half2_rn(q.e.w);
        H2U a0, a1, a2, a3; a0.u = tv.x; a1.u = tv.y; a2.u = tv.z; a3.u = tv.w;
        acc[0][0] = __hfma2(a0.h2, ww, acc[0][0]);
        acc[0][1] = __hfma2(a1.h2, ww, acc[0][1]);
        acc[0][2] = __hfma2(a2.h2, ww, acc[0][2]);
        acc[0][3] = __hfma2(a3.h2, ww, acc[0][3]);
    }
    if (p < end) {
        int idx = p + qtr;
        int cl = (idx < end) ? idx : end - 1;
        EdgePair q; q.u = __builtin_nontemporal_load(&cvu[cl]);
        float wq = (idx < end) ? q.e.w : 0.f;
        uint4 tv = *(const uint4*)&t[(size_t)q.e.s * FEAT + 8 * l4];
        __half2 ww = __float2half2_rn(wq);
        H2U a0, a1, a2, a3; a0.u = tv.x; a1.u = tv.y; a2.u = tv.z; a3.u = tv.w;
        acc[1][0] = __hfma2(a0.h2, ww, acc[1][0]);
        acc[1][1] = __hfma2(a1.h2, ww, acc[1][1]);
        acc[1][2] = __hfma2(a2.h2, ww, acc[1][2]);
        acc[1][3] = __hfma2(a3.h2, ww, acc[1][3]);
    }
    float2 s[4];
#pragma unroll
    for (int k = 0; k < 4; ++k) {
        float2 f0 = __half22float2(acc[0][k]);
        float2 f1 = __half22float2(acc[1][k]);
        float2 f2 = __half22float2(acc[2][k]);
        float2 f3 = __half22float2(acc[3][k]);
        s[k].x = (f0.x + f1.x) + (f2.x + f3.x);
        s[k].y = (f0.y + f1.y) + (f2.y + f3.y);
        s[k].x += __shfl_xor(s[k].x, 16, 64);
        s[k].y += __shfl_xor(s[k].y, 16, 64);
        s[k].x += __shfl_xor(s[k].x, 32, 64);
        s[k].y += __shfl_xor(s[k].y, 32, 64);
    }
    // all lanes now hold the full row sums for feats 8*l4..8*l4+7
    float dd = dis[wv];
    float4 b0 = *(const float4*)&bias[8 * l4];
    float4 b1 = *(const float4*)&bias[8 * l4 + 4];
    float h[8];
    h[0] = fmaxf(fmaf(dd, s[0].x, b0.x), 0.f);
    h[1] = fmaxf(fmaf(dd, s[0].y, b0.y), 0.f);
    h[2] = fmaxf(fmaf(dd, s[1].x, b0.z), 0.f);
    h[3] = fmaxf(fmaf(dd, s[1].y, b0.w), 0.f);
    h[4] = fmaxf(fmaf(dd, s[2].x, b1.x), 0.f);
    h[5] = fmaxf(fmaf(dd, s[2].y, b1.y), 0.f);
    h[6] = fmaxf(fmaf(dd, s[3].x, b1.z), 0.f);
    h[7] = fmaxf(fmaf(dd, s[3].y, b1.w), 0.f);
    float4 par = {0.f, 0.f, 0.f, 0.f};
#pragma unroll
    for (int i = 0; i < 8; ++i) {
        float4 wr = *(const float4*)&Wc[(8 * l4 + i) * 4];
        par.x = fmaf(h[i], wr.x, par.x);
        par.y = fmaf(h[i], wr.y, par.y);
        par.z = fmaf(h[i], wr.z, par.z);
        par.w = fmaf(h[i], wr.w, par.w);
    }
#pragma unroll
    for (int mask = 1; mask < 16; mask <<= 1) {
        par.x += __shfl_xor(par.x, mask, 64);
        par.y += __shfl_xor(par.y, mask, 64);
        par.z += __shfl_xor(par.z, mask, 64);
        par.w += __shfl_xor(par.w, mask, 64);
    }
    if (lane == 0) {
        par.x *= dd; par.y *= dd; par.z *= dd; par.w *= dd;   // outer dis for layer-3 prop
        *(float4*)&z[(size_t)wv * 4] = par;
    }
}

// ---------------- graph segment boundaries (batch is sorted) ----------------
__global__ void gbound_kernel(const int* __restrict__ batch, int* __restrict__ gstart,
                              int n, int G_) {
    int i = blockIdx.x * blockDim.x + threadIdx.x;
    if (i >= n) return;
    int b = batch[i];
    int prev = (i == 0) ? -1 : batch[i - 1];
    for (int g = prev + 1; g <= b; ++g) gstart[g] = i;
    if (i == n - 1) {
        for (int g = b + 1; g <= G_; ++g) gstart[g] = n;
    }
}

// ---------------- combined head weights ----------------
__global__ void wcomb_kernel(const float* __restrict__ W2, const float* __restrict__ Wp,
                             const float* __restrict__ b2, const float* __restrict__ bp,
                             float* Wc, float* bc) {
    int tid = blockIdx.x * blockDim.x + threadIdx.x;
    if (tid < 512) {
        int c = tid >> 2, k = tid & 3;
        float s = 0.f;
        for (int j = 0; j < 200; ++j) s = fmaf(W2[c * 200 + j], Wp[j * 4 + k], s);
        Wc[tid] = s;
    }
    if (tid < 4) {
        float s = bp[tid];
        for (int j = 0; j < 200; ++j) s = fmaf(b2[j], Wp[j * 4 + tid], s);
        bc[tid] = s;
    }
}

// ---------------- CSR propagate, 4 feats: thread/node ----------------
__global__ __launch_bounds__(256) void prop4_kernel(const int* __restrict__ rp,
                                                    const int2* __restrict__ cv,
                                                    const float* __restrict__ dis,
                                                    const float* __restrict__ z,
                                                    float* __restrict__ z2, int n) {
    int i = blockIdx.x * blockDim.x + threadIdx.x;
    if (i >= n) return;
    int beg = rp[i], end = rp[i + 1];
    float4 a0 = {0.f, 0.f, 0.f, 0.f}, a1 = {0.f, 0.f, 0.f, 0.f};
    int p = beg;
    for (; p + 2 <= end; p += 2) {
        EdgePair q0, q1; q0.i2 = cv[p]; q1.i2 = cv[p + 1];
        float4 v0 = *(const float4*)&z[(size_t)q0.e.s * 4];
        float4 v1 = *(const float4*)&z[(size_t)q1.e.s * 4];
        a0.x = fmaf(v0.x, q0.e.w, a0.x); a0.y = fmaf(v0.y, q0.e.w, a0.y);
        a0.z = fmaf(v0.z, q0.e.w, a0.z); a0.w = fmaf(v0.w, q0.e.w, a0.w);
        a1.x = fmaf(v1.x, q1.e.w, a1.x); a1.y = fmaf(v1.y, q1.e.w, a1.y);
        a1.z = fmaf(v1.z, q1.e.w, a1.z); a1.w = fmaf(v1.w, q1.e.w, a1.w);
    }
    if (p < end) {
        EdgePair q; q.i2 = cv[p];
        float4 v = *(const float4*)&z[(size_t)q.e.s * 4];
        a0.x = fmaf(v.x, q.e.w, a0.x); a0.y = fmaf(v.y, q.e.w, a0.y);
        a0.z = fmaf(v.z, q.e.w, a0.z); a0.w = fmaf(v.w, q.e.w, a0.w);
    }
    float dd = dis[i];
    a0.x = dd * (a0.x + a1.x); a0.y = dd * (a0.y + a1.y);
    a0.z = dd * (a0.z + a1.z); a0.w = dd * (a0.w + a1.w);
    *(float4*)&z2[(size_t)i * 4] = a0;
}

// ---------------- segment mean-pool on 4 feats + bias -> out[G x 4] ----------------
__global__ __launch_bounds__(256) void pool4_kernel(const float* __restrict__ z2,
                                                    const int* __restrict__ gstart,
                                                    const float* __restrict__ bc,
                                                    float* __restrict__ out, int G_) {
    __shared__ float sd[256];
    int g = blockIdx.x;
    int k = threadIdx.x & 3;
    int sub = threadIdx.x >> 2;
    int beg = gstart[g], end = gstart[g + 1];
    float s = 0.f;
    for (int i = beg + sub; i < end; i += 64) s += z2[(size_t)i * 4 + k];
    sd[threadIdx.x] = s;
    __syncthreads();
    for (int off = 32; off > 0; off >>= 1) {
        if (sub < off) sd[threadIdx.x] += sd[threadIdx.x + off * 4];
        __syncthreads();
    }
    if (sub == 0) {
        int c = end - beg;
        out[g * 4 + k] = sd[k] / (float)max(c, 1) + bc[k];
    }
}

extern "C" void kernel_launch(void* const* d_in, const int* in_sizes, int n_in,
                              void* d_out, int out_size, void* d_ws, size_t ws_size,
                              hipStream_t stream) {
    const float* x    = (const float*)d_in[0];
    const int*   ei   = (const int*)d_in[1];
    const float* eatt = (const float*)d_in[2];
    const int*   batch= (const int*)d_in[3];
    const float* W0   = (const float*)d_in[4];
    const float* b0   = (const float*)d_in[5];
    const float* W1   = (const float*)d_in[6];
    const float* b1   = (const float*)d_in[7];
    const float* W2   = (const float*)d_in[8];
    const float* b2   = (const float*)d_in[9];
    const float* Wp   = (const float*)d_in[10];
    const float* bp   = (const float*)d_in[11];
    float* out = (float*)d_out;

    const int Nn = in_sizes[0] / FEAT;        // 100000
    const int E_ = in_sizes[2];               // 1600000
    const int G_ = out_size / 4;              // 500
    const int NNZ = E_ + Nn;
    const int NB = ((Nn - 1) >> BSH) + 1;     // 391 buckets

    const int* e_src = ei;
    const int* e_dst = ei + E_;

    // ---- workspace layout ----
    char* ws = (char*)d_ws;
    size_t off = 0;
    auto alloc = [&](size_t bytes) { void* p = ws + off; off = (off + bytes + 255) & ~(size_t)255; return p; };
    float* dis     = (float*)alloc((size_t)Nn * 4);
    int*   cnt     = (int*)  alloc((size_t)Nn * 4);
    int*   rp      = (int*)  alloc((size_t)(Nn + 1) * 4);
    int*   bsum    = (int*)  alloc(1024 * 4);
    int*   gcnt    = (int*)  alloc((size_t)NB * 4);
    int2*  cv      = (int2*) alloc((size_t)NNZ * 8);
    unsigned short* bufA = (unsigned short*)alloc((size_t)NB * BCAP * 8);  // h1 f16; aliases bins (25.6 MB)
    unsigned short* bufB = (unsigned short*)alloc((size_t)Nn * FEAT * 2);  // t1/t2 f16
    int*   gstart  = (int*)  alloc((size_t)(G_ + 1) * 4);
    float* z       = (float*)alloc((size_t)Nn * 4 * 4);
    float* z2      = (float*)alloc((size_t)Nn * 4 * 4);
    float* Wc      = (float*)alloc(512 * 4);
    float* bc      = (float*)alloc(4 * 4);
    int2*  bins    = (int2*)bufA;   // dead before prop1 writes bufA
    (void)ws_size;

    const int T = 256;
    auto cdiv = [](int a, int b) { return (a + b - 1) / b; };

    // small independent preps
    wcomb_kernel<<<2, T, 0, stream>>>(W2, Wp, b2, bp, Wc, bc);
    gbound_kernel<<<cdiv(Nn, T), T, 0, stream>>>(batch, gstart, Nn, G_);

    // CSR build via multisplit (+ fused deg->dis in scat2)
    (void)hipMemsetAsync(gcnt, 0, (size_t)NB * 4, stream);
    bin1_kernel<<<cdiv(E_, 4096), T, 0, stream>>>(e_src, e_dst, eatt, gcnt, bins, E_, NB);
    cnt2_kernel<<<NB, T, 0, stream>>>(bins, gcnt, cnt, Nn);
    int nb = cdiv(Nn, 1024);
    scan_blk<<<nb, T, 0, stream>>>(cnt, rp, bsum, Nn);
    scan_top<<<1, T, 0, stream>>>(bsum, nb);
    scan_add<<<cdiv(Nn, T), T, 0, stream>>>(rp, bsum, Nn, NNZ);
    scat2_kernel<<<NB, T, 0, stream>>>(bins, gcnt, rp, cv, dis, Nn);

    // layer 1: bufB = f16(dis .* (x@W0)); bufA = f16(relu(dis .* ((A+I)@bufB) + b0))
    gemm_f32in<<<cdiv(Nn, 64), T, 0, stream>>>(x, W0, dis, bufB, Nn);
    prop_kernel<<<cdiv(Nn * 64, T), T, 0, stream>>>(rp, cv, dis, bufB, b0, bufA, Nn);

    // layer 2 + head projection fused: bufB = f16(dis .* (bufA@W1)); z = dis .* (relu(...)@Wc)
    gemm_f16in<<<cdiv(Nn, 64), T, 0, stream>>>(bufA, W1, dis, bufB, Nn);
    prop_zk_kernel<<<cdiv(Nn * 64, T), T, 0, stream>>>(rp, cv, dis, bufB, b1, Wc, z, Nn);

    // layer 3 + pool
    prop4_kernel<<<cdiv(Nn, T), T, 0, stream>>>(rp, cv, dis, z, z2, Nn);
    pool4_kernel<<<G_, T, 0, stream>>>(z2, gstart, bc, out, G_);
}

// Round 10
// 457.478 us; speedup vs baseline: 1.0813x; 1.0813x over previous
//
#include <hip/hip_runtime.h>
#include <hip/hip_bf16.h>
#include <hip/hip_fp16.h>

// GCN, dis-folded: A_norm = D^-1/2 (A_w + I) D^-1/2; CSR stores raw w.
// R10: R8's half-wave access pattern (2 edges/wave-instr, uint2/lane — 91us proven)
//      + R9's f16/hfma2 numerics (no unpack VALU — absmax 6.1e-5 proven).
//      R9's quarter-wave 4-row gathers regressed (per-instr coalescing cost).

#define FEAT 128
#define BSH 8                 // bucket shift
#define BCAP 8192             // entries per bucket (mean 4092)

typedef union { int2 i2; long long u; struct { int s; float w; } e; } EdgePair;
typedef union { unsigned u; __half2 h2; } H2U;

__device__ __forceinline__ unsigned pack2h(float a, float b) {
    return (unsigned)__half_as_ushort(__float2half_rn(a)) |
           ((unsigned)__half_as_ushort(__float2half_rn(b)) << 16);   // RNE both
}

// ---------------- pass 1: bin edges by dst>>8 ----------------
__global__ __launch_bounds__(256) void bin1_kernel(const int* __restrict__ src,
                                                   const int* __restrict__ dst,
                                                   const float* __restrict__ w,
                                                   int* __restrict__ gcnt,
                                                   int2* __restrict__ bins,
                                                   int E_, int NB) {
    __shared__ int lh[392], lbase[392], lcur[392];
    const int CHUNK = 4096;
    int base = blockIdx.x * CHUNK;
    for (int t = threadIdx.x; t < NB; t += 256) { lh[t] = 0; lcur[t] = 0; }
    __syncthreads();
    int ds[16];
#pragma unroll
    for (int j = 0; j < 16; ++j) {
        int e = base + j * 256 + threadIdx.x;
        ds[j] = (e < E_) ? dst[e] : -1;
        if (ds[j] >= 0) atomicAdd(&lh[ds[j] >> BSH], 1);
    }
    __syncthreads();
    for (int t = threadIdx.x; t < NB; t += 256)
        if (lh[t] > 0) lbase[t] = atomicAdd(&gcnt[t], lh[t]);
    __syncthreads();
#pragma unroll
    for (int j = 0; j < 16; ++j) {
        int e = base + j * 256 + threadIdx.x;
        if (ds[j] >= 0) {
            int b = ds[j] >> BSH;
            int idx = lbase[b] + atomicAdd(&lcur[b], 1);
            if (idx < BCAP) {
                EdgePair p;
                p.e.s = src[e] | ((ds[j] & 255) << 20);
                p.e.w = w[e];
                bins[(size_t)b * BCAP + idx] = p.i2;
            }
        }
    }
}

// ---------------- pass 2a: per-node counts from bins ----------------
__global__ __launch_bounds__(256) void cnt2_kernel(const int2* __restrict__ bins,
                                                   const int* __restrict__ gcnt,
                                                   int* __restrict__ cnt, int n) {
    __shared__ int lh[256];
    int b = blockIdx.x;
    lh[threadIdx.x] = 0;
    __syncthreads();
    int m = min(gcnt[b], BCAP);
    const int2* bp = bins + (size_t)b * BCAP;
    for (int i = threadIdx.x; i < m; i += 256) {
        unsigned p = (unsigned)bp[i].x;
        atomicAdd(&lh[p >> 20], 1);
    }
    __syncthreads();
    int node = (b << BSH) + threadIdx.x;
    if (node < n) cnt[node] = lh[threadIdx.x] + 1;   // +1 self-loop
}

// ---------------- exclusive scan (compact, 3-phase, chunk=1024) ----------------
__global__ __launch_bounds__(256) void scan_blk(const int* __restrict__ in, int* __restrict__ out,
                                                int* __restrict__ bsum, int n) {
    __shared__ int sd[256];
    int tid = threadIdx.x;
    int base = blockIdx.x * 1024 + tid * 4;
    int v[4];
#pragma unroll
    for (int i = 0; i < 4; ++i) v[i] = (base + i < n) ? in[base + i] : 0;
    int tot = v[0] + v[1] + v[2] + v[3];
    sd[tid] = tot; __syncthreads();
    for (int off = 1; off < 256; off <<= 1) {
        int x = (tid >= off) ? sd[tid - off] : 0;
        __syncthreads();
        sd[tid] += x;
        __syncthreads();
    }
    int excl = sd[tid] - tot;
    if (tid == 255) bsum[blockIdx.x] = sd[255];
    int run = excl;
#pragma unroll
    for (int i = 0; i < 4; ++i) { if (base + i < n) out[base + i] = run; run += v[i]; }
}

__global__ __launch_bounds__(256) void scan_top(int* __restrict__ bsum, int nb) {
    __shared__ int sd[256];
    int tid = threadIdx.x;
    int v[4];
#pragma unroll
    for (int i = 0; i < 4; ++i) {
        int idx = tid * 4 + i;
        v[i] = (idx < nb) ? bsum[idx] : 0;
    }
    int tot = v[0] + v[1] + v[2] + v[3];
    sd[tid] = tot; __syncthreads();
    for (int off = 1; off < 256; off <<= 1) {
        int x = (tid >= off) ? sd[tid - off] : 0;
        __syncthreads();
        sd[tid] += x;
        __syncthreads();
    }
    int excl = sd[tid] - tot;
    int run = excl;
#pragma unroll
    for (int i = 0; i < 4; ++i) {
        int idx = tid * 4 + i;
        if (idx < nb) bsum[idx] = run;
        run += v[i];
    }
}

__global__ void scan_add(int* __restrict__ rp, const int* __restrict__ bsum, int n, int total) {
    int idx = blockIdx.x * blockDim.x + threadIdx.x;
    if (idx < n) rp[idx] += bsum[idx >> 10];
    if (idx == 0) rp[n] = total;
}

// ---------------- pass 2b: drain buckets -> cv; fused per-node deg -> dis ----------------
__global__ __launch_bounds__(256) void scat2_kernel(const int2* __restrict__ bins,
                                                    const int* __restrict__ gcnt,
                                                    const int* __restrict__ rp,
                                                    int2* __restrict__ cv,
                                                    float* __restrict__ dis, int n) {
    __shared__ int lcur[256];
    __shared__ float wsum[256];
    int b = blockIdx.x;
    int node0 = b << BSH;
    int node = node0 + threadIdx.x;
    lcur[threadIdx.x] = (node < n) ? rp[node] : 0;
    wsum[threadIdx.x] = 1.0f;   // self-loop weight
    __syncthreads();
    int m = min(gcnt[b], BCAP);
    const int2* bp = bins + (size_t)b * BCAP;
    for (int i = threadIdx.x; i < m; i += 256) {
        int2 raw = bp[i];
        unsigned pk = (unsigned)raw.x;
        int dlo = pk >> 20;
        int pos = atomicAdd(&lcur[dlo], 1);
        atomicAdd(&wsum[dlo], __int_as_float(raw.y));
        EdgePair q; q.e.s = (int)(pk & 0xFFFFF); q.i2.y = raw.y;
        cv[pos] = q.i2;
    }
    __syncthreads();
    if (node < n) {                       // self-loop entry, w = 1
        int pos = atomicAdd(&lcur[threadIdx.x], 1);
        EdgePair q; q.e.s = node; q.e.w = 1.0f;
        cv[pos] = q.i2;
        dis[node] = rsqrtf(fmaxf(wsum[threadIdx.x], 1e-12f));
    }
}

// ---------------- GEMM1: C_f16[M x 128] = rowscale .* (A_f32 @ B) ----------------
__global__ __launch_bounds__(256) void gemm_f32in(const float* __restrict__ A,
                                                  const float* __restrict__ B,
                                                  const float* __restrict__ rowscale,
                                                  unsigned short* __restrict__ C, int M) {
    __shared__ float As[32][64];
    __shared__ float Bs[32][128];
    int tid = threadIdx.x;
    int row0 = blockIdx.x * 64;
    int tx = tid & 15;
    int ty = tid >> 4;
    float acc[4][8] = {};
    int a_r = tid >> 3;
    int a_c = (tid & 7) << 2;
    int b_r = tid >> 5;
    int b_c = (tid & 31) << 2;
    for (int k0 = 0; k0 < 128; k0 += 32) {
#pragma unroll
        for (int i = 0; i < 2; ++i) {
            int r = a_r + i * 32;
            int gr = row0 + r;
            float4 v = (gr < M) ? *(const float4*)&A[(size_t)gr * 128 + k0 + a_c]
                                : make_float4(0.f, 0.f, 0.f, 0.f);
            As[a_c + 0][r] = v.x; As[a_c + 1][r] = v.y;
            As[a_c + 2][r] = v.z; As[a_c + 3][r] = v.w;
        }
#pragma unroll
        for (int i = 0; i < 4; ++i) {
            int r = b_r + i * 8;
            *(float4*)&Bs[r][b_c] = *(const float4*)&B[(size_t)(k0 + r) * 128 + b_c];
        }
        __syncthreads();
#pragma unroll
        for (int k = 0; k < 32; ++k) {
            float4 a  = *(const float4*)&As[k][ty * 4];
            float4 bv0 = *(const float4*)&Bs[k][tx * 8];
            float4 bv1 = *(const float4*)&Bs[k][tx * 8 + 4];
            float av[4] = {a.x, a.y, a.z, a.w};
            float bv[8] = {bv0.x, bv0.y, bv0.z, bv0.w, bv1.x, bv1.y, bv1.z, bv1.w};
#pragma unroll
            for (int i = 0; i < 4; ++i)
#pragma unroll
                for (int j = 0; j < 8; ++j)
                    acc[i][j] = fmaf(av[i], bv[j], acc[i][j]);
        }
        __syncthreads();
    }
#pragma unroll
    for (int i = 0; i < 4; ++i) {
        int gr = row0 + ty * 4 + i;
        if (gr < M) {
            float sc = rowscale[gr];
            uint4 pk;
            pk.x = pack2h(sc * acc[i][0], sc * acc[i][1]);
            pk.y = pack2h(sc * acc[i][2], sc * acc[i][3]);
            pk.z = pack2h(sc * acc[i][4], sc * acc[i][5]);
            pk.w = pack2h(sc * acc[i][6], sc * acc[i][7]);
            *(uint4*)&C[(size_t)gr * 128 + tx * 8] = pk;
        }
    }
}

// ---------------- GEMM2: C_f16[M x 128] = rowscale .* (A_f16 @ B) ----------------
__global__ __launch_bounds__(256) void gemm_f16in(const unsigned short* __restrict__ A,
                                                  const float* __restrict__ B,
                                                  const float* __restrict__ rowscale,
                                                  unsigned short* __restrict__ C, int M) {
    __shared__ float As[32][64];
    __shared__ float Bs[32][128];
    int tid = threadIdx.x;
    int row0 = blockIdx.x * 64;
    int tx = tid & 15;
    int ty = tid >> 4;
    float acc[4][8] = {};
    int a_r = tid >> 3;
    int a_c = (tid & 7) << 2;
    int b_r = tid >> 5;
    int b_c = (tid & 31) << 2;
    for (int k0 = 0; k0 < 128; k0 += 32) {
#pragma unroll
        for (int i = 0; i < 2; ++i) {
            int r = a_r + i * 32;
            int gr = row0 + r;
            uint2 v = (gr < M) ? *(const uint2*)&A[(size_t)gr * 128 + k0 + a_c]
                               : make_uint2(0u, 0u);
            H2U u0, u1; u0.u = v.x; u1.u = v.y;
            float2 f0 = __half22float2(u0.h2);
            float2 f1 = __half22float2(u1.h2);
            As[a_c + 0][r] = f0.x; As[a_c + 1][r] = f0.y;
            As[a_c + 2][r] = f1.x; As[a_c + 3][r] = f1.y;
        }
#pragma unroll
        for (int i = 0; i < 4; ++i) {
            int r = b_r + i * 8;
            *(float4*)&Bs[r][b_c] = *(const float4*)&B[(size_t)(k0 + r) * 128 + b_c];
        }
        __syncthreads();
#pragma unroll
        for (int k = 0; k < 32; ++k) {
            float4 a  = *(const float4*)&As[k][ty * 4];
            float4 bv0 = *(const float4*)&Bs[k][tx * 8];
            float4 bv1 = *(const float4*)&Bs[k][tx * 8 + 4];
            float av[4] = {a.x, a.y, a.z, a.w};
            float bv[8] = {bv0.x, bv0.y, bv0.z, bv0.w, bv1.x, bv1.y, bv1.z, bv1.w};
#pragma unroll
            for (int i = 0; i < 4; ++i)
#pragma unroll
                for (int j = 0; j < 8; ++j)
                    acc[i][j] = fmaf(av[i], bv[j], acc[i][j]);
        }
        __syncthreads();
    }
#pragma unroll
    for (int i = 0; i < 4; ++i) {
        int gr = row0 + ty * 4 + i;
        if (gr < M) {
            float sc = rowscale[gr];
            uint4 pk;
            pk.x = pack2h(sc * acc[i][0], sc * acc[i][1]);
            pk.y = pack2h(sc * acc[i][2], sc * acc[i][3]);
            pk.z = pack2h(sc * acc[i][4], sc * acc[i][5]);
            pk.w = pack2h(sc * acc[i][6], sc * acc[i][7]);
            *(uint4*)&C[(size_t)gr * 128 + tx * 8] = pk;
        }
    }
}

// ---------------- CSR propagate, 128 f16 feats (layer 1) ----------------
// wave/node; half-wave: 32 lanes x 4 f16 (uint2) per edge, 2 edges/wave-instr;
// 8 edges in flight; packed __hfma2 accumulation.
__global__ __launch_bounds__(256) void prop_kernel(const int* __restrict__ rp,
                                                   const int2* __restrict__ cv,
                                                   const float* __restrict__ dis,
                                                   const unsigned short* __restrict__ t,
                                                   const float* __restrict__ bias,
                                                   unsigned short* __restrict__ out, int n) {
    const long long* cvu = (const long long*)cv;
    int wv = (blockIdx.x * blockDim.x + threadIdx.x) >> 6;
    int lane = threadIdx.x & 63;
    if (wv >= n) return;
    int half = lane >> 5, l5 = lane & 31;
    int beg = rp[wv], end = rp[wv + 1];
    __half2 zh = __float2half2_rn(0.f);
    __half2 acc[4][2];
#pragma unroll
    for (int j = 0; j < 4; ++j) { acc[j][0] = zh; acc[j][1] = zh; }
    int p = beg;
    for (; p + 8 <= end; p += 8) {
        EdgePair q[4];
#pragma unroll
        for (int j = 0; j < 4; ++j) q[j].u = __builtin_nontemporal_load(&cvu[p + 2 * j + half]);
        uint2 tv[4];
#pragma unroll
        for (int j = 0; j < 4; ++j) tv[j] = *(const uint2*)&t[(size_t)q[j].e.s * FEAT + 4 * l5];
#pragma unroll
        for (int j = 0; j < 4; ++j) {
            __half2 ww = __float2half2_rn(q[j].e.w);
            H2U a0, a1; a0.u = tv[j].x; a1.u = tv[j].y;
            acc[j][0] = __hfma2(a0.h2, ww, acc[j][0]);
            acc[j][1] = __hfma2(a1.h2, ww, acc[j][1]);
        }
    }
    for (; p + 2 <= end; p += 2) {
        EdgePair q; q.u = __builtin_nontemporal_load(&cvu[p + half]);
        uint2 tv = *(const uint2*)&t[(size_t)q.e.s * FEAT + 4 * l5];
        __half2 ww = __float2half2_rn(q.e.w);
        H2U a0, a1; a0.u = tv.x; a1.u = tv.y;
        acc[0][0] = __hfma2(a0.h2, ww, acc[0][0]);
        acc[0][1] = __hfma2(a1.h2, ww, acc[0][1]);
    }
    if (p < end) {
        EdgePair q; q.u = __builtin_nontemporal_load(&cvu[p]);
        float wq = half ? 0.f : q.e.w;
        uint2 tv = *(const uint2*)&t[(size_t)q.e.s * FEAT + 4 * l5];
        __half2 ww = __float2half2_rn(wq);
        H2U a0, a1; a0.u = tv.x; a1.u = tv.y;
        acc[1][0] = __hfma2(a0.h2, ww, acc[1][0]);
        acc[1][1] = __hfma2(a1.h2, ww, acc[1][1]);
    }
    float2 s01, s23;
    {
        float2 f0 = __half22float2(acc[0][0]);
        float2 f1 = __half22float2(acc[1][0]);
        float2 f2 = __half22float2(acc[2][0]);
        float2 f3 = __half22float2(acc[3][0]);
        s01.x = (f0.x + f1.x) + (f2.x + f3.x);
        s01.y = (f0.y + f1.y) + (f2.y + f3.y);
        f0 = __half22float2(acc[0][1]);
        f1 = __half22float2(acc[1][1]);
        f2 = __half22float2(acc[2][1]);
        f3 = __half22float2(acc[3][1]);
        s23.x = (f0.x + f1.x) + (f2.x + f3.x);
        s23.y = (f0.y + f1.y) + (f2.y + f3.y);
    }
    s01.x += __shfl_xor(s01.x, 32, 64);
    s01.y += __shfl_xor(s01.y, 32, 64);
    s23.x += __shfl_xor(s23.x, 32, 64);
    s23.y += __shfl_xor(s23.y, 32, 64);
    if (half == 0) {
        float dd = dis[wv];
        float4 b = *(const float4*)&bias[4 * l5];
        float r0 = fmaxf(fmaf(dd, s01.x, b.x), 0.f);
        float r1 = fmaxf(fmaf(dd, s01.y, b.y), 0.f);
        float r2 = fmaxf(fmaf(dd, s23.x, b.z), 0.f);
        float r3 = fmaxf(fmaf(dd, s23.y, b.w), 0.f);
        uint2 pk;
        pk.x = pack2h(r0, r1);
        pk.y = pack2h(r2, r3);
        *(uint2*)&out[(size_t)wv * FEAT + 4 * l5] = pk;
    }
}

// ---------------- layer-2 prop fused with head projection (f16 t) ----------------
// z[i] = dis[i] * (relu(dis[i]*((A+I)@t)[i] + b1) @ Wc)
__global__ __launch_bounds__(256) void prop_zk_kernel(const int* __restrict__ rp,
                                                      const int2* __restrict__ cv,
                                                      const float* __restrict__ dis,
                                                      const unsigned short* __restrict__ t,
                                                      const float* __restrict__ bias,
                                                      const float* __restrict__ Wc,
                                                      float* __restrict__ z, int n) {
    const long long* cvu = (const long long*)cv;
    int wv = (blockIdx.x * blockDim.x + threadIdx.x) >> 6;
    int lane = threadIdx.x & 63;
    if (wv >= n) return;
    int half = lane >> 5, l5 = lane & 31;
    int beg = rp[wv], end = rp[wv + 1];
    __half2 zh = __float2half2_rn(0.f);
    __half2 acc[4][2];
#pragma unroll
    for (int j = 0; j < 4; ++j) { acc[j][0] = zh; acc[j][1] = zh; }
    int p = beg;
    for (; p + 8 <= end; p += 8) {
        EdgePair q[4];
#pragma unroll
        for (int j = 0; j < 4; ++j) q[j].u = __builtin_nontemporal_load(&cvu[p + 2 * j + half]);
        uint2 tv[4];
#pragma unroll
        for (int j = 0; j < 4; ++j) tv[j] = *(const uint2*)&t[(size_t)q[j].e.s * FEAT + 4 * l5];
#pragma unroll
        for (int j = 0; j < 4; ++j) {
            __half2 ww = __float2half2_rn(q[j].e.w);
            H2U a0, a1; a0.u = tv[j].x; a1.u = tv[j].y;
            acc[j][0] = __hfma2(a0.h2, ww, acc[j][0]);
            acc[j][1] = __hfma2(a1.h2, ww, acc[j][1]);
        }
    }
    for (; p + 2 <= end; p += 2) {
        EdgePair q; q.u = __builtin_nontemporal_load(&cvu[p + half]);
        uint2 tv = *(const uint2*)&t[(size_t)q.e.s * FEAT + 4 * l5];
        __half2 ww = __float2half2_rn(q.e.w);
        H2U a0, a1; a0.u = tv.x; a1.u = tv.y;
        acc[0][0] = __hfma2(a0.h2, ww, acc[0][0]);
        acc[0][1] = __hfma2(a1.h2, ww, acc[0][1]);
    }
    if (p < end) {
        EdgePair q; q.u = __builtin_nontemporal_load(&cvu[p]);
        float wq = half ? 0.f : q.e.w;
        uint2 tv = *(const uint2*)&t[(size_t)q.e.s * FEAT + 4 * l5];
        __half2 ww = __float2half2_rn(wq);
        H2U a0, a1; a0.u = tv.x; a1.u = tv.y;
        acc[1][0] = __hfma2(a0.h2, ww, acc[1][0]);
        acc[1][1] = __hfma2(a1.h2, ww, acc[1][1]);
    }
    float2 s01, s23;
    {
        float2 f0 = __half22float2(acc[0][0]);
        float2 f1 = __half22float2(acc[1][0]);
        float2 f2 = __half22float2(acc[2][0]);
        float2 f3 = __half22float2(acc[3][0]);
        s01.x = (f0.x + f1.x) + (f2.x + f3.x);
        s01.y = (f0.y + f1.y) + (f2.y + f3.y);
        f0 = __half22float2(acc[0][1]);
        f1 = __half22float2(acc[1][1]);
        f2 = __half22float2(acc[2][1]);
        f3 = __half22float2(acc[3][1]);
        s23.x = (f0.x + f1.x) + (f2.x + f3.x);
        s23.y = (f0.y + f1.y) + (f2.y + f3.y);
    }
    s01.x += __shfl_xor(s01.x, 32, 64);
    s01.y += __shfl_xor(s01.y, 32, 64);
    s23.x += __shfl_xor(s23.x, 32, 64);
    s23.y += __shfl_xor(s23.y, 32, 64);
    float dd = dis[wv];
    float4 b = *(const float4*)&bias[4 * l5];
    float h0 = fmaxf(fmaf(dd, s01.x, b.x), 0.f);
    float h1 = fmaxf(fmaf(dd, s01.y, b.y), 0.f);
    float h2 = fmaxf(fmaf(dd, s23.x, b.z), 0.f);
    float h3 = fmaxf(fmaf(dd, s23.y, b.w), 0.f);
    float4 w0 = *(const float4*)&Wc[16 * l5];
    float4 w1 = *(const float4*)&Wc[16 * l5 + 4];
    float4 w2 = *(const float4*)&Wc[16 * l5 + 8];
    float4 w3 = *(const float4*)&Wc[16 * l5 + 12];
    float4 par;
    par.x = fmaf(h0, w0.x, fmaf(h1, w1.x, fmaf(h2, w2.x, h3 * w3.x)));
    par.y = fmaf(h0, w0.y, fmaf(h1, w1.y, fmaf(h2, w2.y, h3 * w3.y)));
    par.z = fmaf(h0, w0.z, fmaf(h1, w1.z, fmaf(h2, w2.z, h3 * w3.z)));
    par.w = fmaf(h0, w0.w, fmaf(h1, w1.w, fmaf(h2, w2.w, h3 * w3.w)));
#pragma unroll
    for (int mask = 1; mask < 32; mask <<= 1) {
        par.x += __shfl_xor(par.x, mask, 64);
        par.y += __shfl_xor(par.y, mask, 64);
        par.z += __shfl_xor(par.z, mask, 64);
        par.w += __shfl_xor(par.w, mask, 64);
    }
    if (lane == 0) {
        par.x *= dd; par.y *= dd; par.z *= dd; par.w *= dd;   // outer dis for layer-3 prop
        *(float4*)&z[(size_t)wv * 4] = par;
    }
}

// ---------------- graph segment boundaries (batch is sorted) ----------------
__global__ void gbound_kernel(const int* __restrict__ batch, int* __restrict__ gstart,
                              int n, int G_) {
    int i = blockIdx.x * blockDim.x + threadIdx.x;
    if (i >= n) return;
    int b = batch[i];
    int prev = (i == 0) ? -1 : batch[i - 1];
    for (int g = prev + 1; g <= b; ++g) gstart[g] = i;
    if (i == n - 1) {
        for (int g = b + 1; g <= G_; ++g) gstart[g] = n;
    }
}

// ---------------- combined head weights ----------------
__global__ void wcomb_kernel(const float* __restrict__ W2, const float* __restrict__ Wp,
                             const float* __restrict__ b2, const float* __restrict__ bp,
                             float* Wc, float* bc) {
    int tid = blockIdx.x * blockDim.x + threadIdx.x;
    if (tid < 512) {
        int c = tid >> 2, k = tid & 3;
        float s = 0.f;
        for (int j = 0; j < 200; ++j) s = fmaf(W2[c * 200 + j], Wp[j * 4 + k], s);
        Wc[tid] = s;
    }
    if (tid < 4) {
        float s = bp[tid];
        for (int j = 0; j < 200; ++j) s = fmaf(b2[j], Wp[j * 4 + tid], s);
        bc[tid] = s;
    }
}

// ---------------- CSR propagate, 4 feats: thread/node ----------------
__global__ __launch_bounds__(256) void prop4_kernel(const int* __restrict__ rp,
                                                    const int2* __restrict__ cv,
                                                    const float* __restrict__ dis,
                                                    const float* __restrict__ z,
                                                    float* __restrict__ z2, int n) {
    int i = blockIdx.x * blockDim.x + threadIdx.x;
    if (i >= n) return;
    int beg = rp[i], end = rp[i + 1];
    float4 a0 = {0.f, 0.f, 0.f, 0.f}, a1 = {0.f, 0.f, 0.f, 0.f};
    int p = beg;
    for (; p + 2 <= end; p += 2) {
        EdgePair q0, q1; q0.i2 = cv[p]; q1.i2 = cv[p + 1];
        float4 v0 = *(const float4*)&z[(size_t)q0.e.s * 4];
        float4 v1 = *(const float4*)&z[(size_t)q1.e.s * 4];
        a0.x = fmaf(v0.x, q0.e.w, a0.x); a0.y = fmaf(v0.y, q0.e.w, a0.y);
        a0.z = fmaf(v0.z, q0.e.w, a0.z); a0.w = fmaf(v0.w, q0.e.w, a0.w);
        a1.x = fmaf(v1.x, q1.e.w, a1.x); a1.y = fmaf(v1.y, q1.e.w, a1.y);
        a1.z = fmaf(v1.z, q1.e.w, a1.z); a1.w = fmaf(v1.w, q1.e.w, a1.w);
    }
    if (p < end) {
        EdgePair q; q.i2 = cv[p];
        float4 v = *(const float4*)&z[(size_t)q.e.s * 4];
        a0.x = fmaf(v.x, q.e.w, a0.x); a0.y = fmaf(v.y, q.e.w, a0.y);
        a0.z = fmaf(v.z, q.e.w, a0.z); a0.w = fmaf(v.w, q.e.w, a0.w);
    }
    float dd = dis[i];
    a0.x = dd * (a0.x + a1.x); a0.y = dd * (a0.y + a1.y);
    a0.z = dd * (a0.z + a1.z); a0.w = dd * (a0.w + a1.w);
    *(float4*)&z2[(size_t)i * 4] = a0;
}

// ---------------- segment mean-pool on 4 feats + bias -> out[G x 4] ----------------
__global__ __launch_bounds__(256) void pool4_kernel(const float* __restrict__ z2,
                                                    const int* __restrict__ gstart,
                                                    const float* __restrict__ bc,
                                                    float* __restrict__ out, int G_) {
    __shared__ float sd[256];
    int g = blockIdx.x;
    int k = threadIdx.x & 3;
    int sub = threadIdx.x >> 2;
    int beg = gstart[g], end = gstart[g + 1];
    float s = 0.f;
    for (int i = beg + sub; i < end; i += 64) s += z2[(size_t)i * 4 + k];
    sd[threadIdx.x] = s;
    __syncthreads();
    for (int off = 32; off > 0; off >>= 1) {
        if (sub < off) sd[threadIdx.x] += sd[threadIdx.x + off * 4];
        __syncthreads();
    }
    if (sub == 0) {
        int c = end - beg;
        out[g * 4 + k] = sd[k] / (float)max(c, 1) + bc[k];
    }
}

extern "C" void kernel_launch(void* const* d_in, const int* in_sizes, int n_in,
                              void* d_out, int out_size, void* d_ws, size_t ws_size,
                              hipStream_t stream) {
    const float* x    = (const float*)d_in[0];
    const int*   ei   = (const int*)d_in[1];
    const float* eatt = (const float*)d_in[2];
    const int*   batch= (const int*)d_in[3];
    const float* W0   = (const float*)d_in[4];
    const float* b0   = (const float*)d_in[5];
    const float* W1   = (const float*)d_in[6];
    const float* b1   = (const float*)d_in[7];
    const float* W2   = (const float*)d_in[8];
    const float* b2   = (const float*)d_in[9];
    const float* Wp   = (const float*)d_in[10];
    const float* bp   = (const float*)d_in[11];
    float* out = (float*)d_out;

    const int Nn = in_sizes[0] / FEAT;        // 100000
    const int E_ = in_sizes[2];               // 1600000
    const int G_ = out_size / 4;              // 500
    const int NNZ = E_ + Nn;
    const int NB = ((Nn - 1) >> BSH) + 1;     // 391 buckets

    const int* e_src = ei;
    const int* e_dst = ei + E_;

    // ---- workspace layout ----
    char* ws = (char*)d_ws;
    size_t off = 0;
    auto alloc = [&](size_t bytes) { void* p = ws + off; off = (off + bytes + 255) & ~(size_t)255; return p; };
    float* dis     = (float*)alloc((size_t)Nn * 4);
    int*   cnt     = (int*)  alloc((size_t)Nn * 4);
    int*   rp      = (int*)  alloc((size_t)(Nn + 1) * 4);
    int*   bsum    = (int*)  alloc(1024 * 4);
    int*   gcnt    = (int*)  alloc((size_t)NB * 4);
    int2*  cv      = (int2*) alloc((size_t)NNZ * 8);
    unsigned short* bufA = (unsigned short*)alloc((size_t)NB * BCAP * 8);  // h1 f16; aliases bins (25.6 MB)
    unsigned short* bufB = (unsigned short*)alloc((size_t)Nn * FEAT * 2);  // t1/t2 f16
    int*   gstart  = (int*)  alloc((size_t)(G_ + 1) * 4);
    float* z       = (float*)alloc((size_t)Nn * 4 * 4);
    float* z2      = (float*)alloc((size_t)Nn * 4 * 4);
    float* Wc      = (float*)alloc(512 * 4);
    float* bc      = (float*)alloc(4 * 4);
    int2*  bins    = (int2*)bufA;   // dead before prop1 writes bufA
    (void)ws_size;

    const int T = 256;
    auto cdiv = [](int a, int b) { return (a + b - 1) / b; };

    // small independent preps
    wcomb_kernel<<<2, T, 0, stream>>>(W2, Wp, b2, bp, Wc, bc);
    gbound_kernel<<<cdiv(Nn, T), T, 0, stream>>>(batch, gstart, Nn, G_);

    // CSR build via multisplit (+ fused deg->dis in scat2)
    (void)hipMemsetAsync(gcnt, 0, (size_t)NB * 4, stream);
    bin1_kernel<<<cdiv(E_, 4096), T, 0, stream>>>(e_src, e_dst, eatt, gcnt, bins, E_, NB);
    cnt2_kernel<<<NB, T, 0, stream>>>(bins, gcnt, cnt, Nn);
    int nb = cdiv(Nn, 1024);
    scan_blk<<<nb, T, 0, stream>>>(cnt, rp, bsum, Nn);
    scan_top<<<1, T, 0, stream>>>(bsum, nb);
    scan_add<<<cdiv(Nn, T), T, 0, stream>>>(rp, bsum, Nn, NNZ);
    scat2_kernel<<<NB, T, 0, stream>>>(bins, gcnt, rp, cv, dis, Nn);

    // layer 1: bufB = f16(dis .* (x@W0)); bufA = f16(relu(dis .* ((A+I)@bufB) + b0))
    gemm_f32in<<<cdiv(Nn, 64), T, 0, stream>>>(x, W0, dis, bufB, Nn);
    prop_kernel<<<cdiv(Nn * 64, T), T, 0, stream>>>(rp, cv, dis, bufB, b0, bufA, Nn);

    // layer 2 + head projection fused: bufB = f16(dis .* (bufA@W1)); z = dis .* (relu(...)@Wc)
    gemm_f16in<<<cdiv(Nn, 64), T, 0, stream>>>(bufA, W1, dis, bufB, Nn);
    prop_zk_kernel<<<cdiv(Nn * 64, T), T, 0, stream>>>(rp, cv, dis, bufB, b1, Wc, z, Nn);

    // layer 3 + pool
    prop4_kernel<<<cdiv(Nn, T), T, 0, stream>>>(rp, cv, dis, z, z2, Nn);
    pool4_kernel<<<G_, T, 0, stream>>>(z2, gstart, bc, out, G_);
}

// Round 11
// 431.027 us; speedup vs baseline: 1.1476x; 1.0614x over previous
//
#include <hip/hip_runtime.h>
#include <hip/hip_bf16.h>
#include <hip/hip_fp16.h>

// GCN, dis-folded: A_norm = D^-1/2 (A_w + I) D^-1/2; CSR stores raw w.
// R11: GEMMs moved to MFMA f16 (16x16x32, fp32 acc). Props unchanged from R10
//      (fabric-floored at 8 XCD x WS). Weights pre-transposed to f16 Wt[n][k].

#define FEAT 128
#define BSH 8                 // bucket shift
#define BCAP 8192             // entries per bucket (mean 4092)

typedef union { int2 i2; long long u; struct { int s; float w; } e; } EdgePair;
typedef union { unsigned u; __half2 h2; } H2U;
typedef _Float16 f16x8 __attribute__((ext_vector_type(8)));
typedef float f32x4 __attribute__((ext_vector_type(4)));

__device__ __forceinline__ unsigned pack2h(float a, float b) {
    return (unsigned)__half_as_ushort(__float2half_rn(a)) |
           ((unsigned)__half_as_ushort(__float2half_rn(b)) << 16);   // RNE both
}

// ---------------- pass 1: bin edges by dst>>8 ----------------
__global__ __launch_bounds__(256) void bin1_kernel(const int* __restrict__ src,
                                                   const int* __restrict__ dst,
                                                   const float* __restrict__ w,
                                                   int* __restrict__ gcnt,
                                                   int2* __restrict__ bins,
                                                   int E_, int NB) {
    __shared__ int lh[392], lbase[392], lcur[392];
    const int CHUNK = 4096;
    int base = blockIdx.x * CHUNK;
    for (int t = threadIdx.x; t < NB; t += 256) { lh[t] = 0; lcur[t] = 0; }
    __syncthreads();
    int ds[16];
#pragma unroll
    for (int j = 0; j < 16; ++j) {
        int e = base + j * 256 + threadIdx.x;
        ds[j] = (e < E_) ? dst[e] : -1;
        if (ds[j] >= 0) atomicAdd(&lh[ds[j] >> BSH], 1);
    }
    __syncthreads();
    for (int t = threadIdx.x; t < NB; t += 256)
        if (lh[t] > 0) lbase[t] = atomicAdd(&gcnt[t], lh[t]);
    __syncthreads();
#pragma unroll
    for (int j = 0; j < 16; ++j) {
        int e = base + j * 256 + threadIdx.x;
        if (ds[j] >= 0) {
            int b = ds[j] >> BSH;
            int idx = lbase[b] + atomicAdd(&lcur[b], 1);
            if (idx < BCAP) {
                EdgePair p;
                p.e.s = src[e] | ((ds[j] & 255) << 20);
                p.e.w = w[e];
                bins[(size_t)b * BCAP + idx] = p.i2;
            }
        }
    }
}

// ---------------- pass 2a: per-node counts from bins ----------------
__global__ __launch_bounds__(256) void cnt2_kernel(const int2* __restrict__ bins,
                                                   const int* __restrict__ gcnt,
                                                   int* __restrict__ cnt, int n) {
    __shared__ int lh[256];
    int b = blockIdx.x;
    lh[threadIdx.x] = 0;
    __syncthreads();
    int m = min(gcnt[b], BCAP);
    const int2* bp = bins + (size_t)b * BCAP;
    for (int i = threadIdx.x; i < m; i += 256) {
        unsigned p = (unsigned)bp[i].x;
        atomicAdd(&lh[p >> 20], 1);
    }
    __syncthreads();
    int node = (b << BSH) + threadIdx.x;
    if (node < n) cnt[node] = lh[threadIdx.x] + 1;   // +1 self-loop
}

// ---------------- exclusive scan (compact, 3-phase, chunk=1024) ----------------
__global__ __launch_bounds__(256) void scan_blk(const int* __restrict__ in, int* __restrict__ out,
                                                int* __restrict__ bsum, int n) {
    __shared__ int sd[256];
    int tid = threadIdx.x;
    int base = blockIdx.x * 1024 + tid * 4;
    int v[4];
#pragma unroll
    for (int i = 0; i < 4; ++i) v[i] = (base + i < n) ? in[base + i] : 0;
    int tot = v[0] + v[1] + v[2] + v[3];
    sd[tid] = tot; __syncthreads();
    for (int off = 1; off < 256; off <<= 1) {
        int x = (tid >= off) ? sd[tid - off] : 0;
        __syncthreads();
        sd[tid] += x;
        __syncthreads();
    }
    int excl = sd[tid] - tot;
    if (tid == 255) bsum[blockIdx.x] = sd[255];
    int run = excl;
#pragma unroll
    for (int i = 0; i < 4; ++i) { if (base + i < n) out[base + i] = run; run += v[i]; }
}

__global__ __launch_bounds__(256) void scan_top(int* __restrict__ bsum, int nb) {
    __shared__ int sd[256];
    int tid = threadIdx.x;
    int v[4];
#pragma unroll
    for (int i = 0; i < 4; ++i) {
        int idx = tid * 4 + i;
        v[i] = (idx < nb) ? bsum[idx] : 0;
    }
    int tot = v[0] + v[1] + v[2] + v[3];
    sd[tid] = tot; __syncthreads();
    for (int off = 1; off < 256; off <<= 1) {
        int x = (tid >= off) ? sd[tid - off] : 0;
        __syncthreads();
        sd[tid] += x;
        __syncthreads();
    }
    int excl = sd[tid] - tot;
    int run = excl;
#pragma unroll
    for (int i = 0; i < 4; ++i) {
        int idx = tid * 4 + i;
        if (idx < nb) bsum[idx] = run;
        run += v[i];
    }
}

__global__ void scan_add(int* __restrict__ rp, const int* __restrict__ bsum, int n, int total) {
    int idx = blockIdx.x * blockDim.x + threadIdx.x;
    if (idx < n) rp[idx] += bsum[idx >> 10];
    if (idx == 0) rp[n] = total;
}

// ---------------- pass 2b: drain buckets -> cv; fused per-node deg -> dis ----------------
__global__ __launch_bounds__(256) void scat2_kernel(const int2* __restrict__ bins,
                                                    const int* __restrict__ gcnt,
                                                    const int* __restrict__ rp,
                                                    int2* __restrict__ cv,
                                                    float* __restrict__ dis, int n) {
    __shared__ int lcur[256];
    __shared__ float wsum[256];
    int b = blockIdx.x;
    int node0 = b << BSH;
    int node = node0 + threadIdx.x;
    lcur[threadIdx.x] = (node < n) ? rp[node] : 0;
    wsum[threadIdx.x] = 1.0f;   // self-loop weight
    __syncthreads();
    int m = min(gcnt[b], BCAP);
    const int2* bp = bins + (size_t)b * BCAP;
    for (int i = threadIdx.x; i < m; i += 256) {
        int2 raw = bp[i];
        unsigned pk = (unsigned)raw.x;
        int dlo = pk >> 20;
        int pos = atomicAdd(&lcur[dlo], 1);
        atomicAdd(&wsum[dlo], __int_as_float(raw.y));
        EdgePair q; q.e.s = (int)(pk & 0xFFFFF); q.i2.y = raw.y;
        cv[pos] = q.i2;
    }
    __syncthreads();
    if (node < n) {                       // self-loop entry, w = 1
        int pos = atomicAdd(&lcur[threadIdx.x], 1);
        EdgePair q; q.e.s = node; q.e.w = 1.0f;
        cv[pos] = q.i2;
        dis[node] = rsqrtf(fmaxf(wsum[threadIdx.x], 1e-12f));
    }
}

// ---------------- weight prep: Wt[n][k] f16 from W[k][n] f32 ----------------
__global__ __launch_bounds__(256) void wprep_kernel(const float* __restrict__ W,
                                                    _Float16* __restrict__ Wt) {
    int tid = blockIdx.x * blockDim.x + threadIdx.x;   // 16384 total
    int nn = tid >> 7, k = tid & 127;
    Wt[nn * 128 + k] = (_Float16)W[k * 128 + nn];
}

// ---------------- MFMA GEMM: C_f16[M x 128] = rowscale .* (A @ W), Wt[n][k] f16 ----------------
// 256 thr = 4 waves; block covers 64 rows; wave w: rows 16w..16w+15, all 128 cols.
// A-frag: A[m=lane&15][k=quad*8+j]; B-frag: Wt[n=lane&15][k=quad*8+j]; D: row=quad*4+r, col=lane&15.
__global__ __launch_bounds__(256) void gemm1_mfma(const float* __restrict__ A,
                                                  const _Float16* __restrict__ Wt,
                                                  const float* __restrict__ rowscale,
                                                  unsigned short* __restrict__ C, int M) {
    int wid = threadIdx.x >> 6, lane = threadIdx.x & 63;
    int quad = lane >> 4, l16 = lane & 15;
    int row0 = blockIdx.x * 64 + wid * 16;
    f32x4 acc[8];
#pragma unroll
    for (int t = 0; t < 8; ++t) acc[t] = (f32x4){0.f, 0.f, 0.f, 0.f};
    int arow = row0 + l16; if (arow >= M) arow = M - 1;   // clamp: pollutes only discarded D rows
    const float* abase = A + (size_t)arow * 128 + quad * 8;
#pragma unroll
    for (int kc = 0; kc < 4; ++kc) {
        float4 a0 = *(const float4*)(abase + kc * 32);
        float4 a1 = *(const float4*)(abase + kc * 32 + 4);
        f16x8 af = { (_Float16)a0.x, (_Float16)a0.y, (_Float16)a0.z, (_Float16)a0.w,
                     (_Float16)a1.x, (_Float16)a1.y, (_Float16)a1.z, (_Float16)a1.w };
#pragma unroll
        for (int t = 0; t < 8; ++t) {
            f16x8 bf = *(const f16x8*)(Wt + (size_t)(t * 16 + l16) * 128 + quad * 8 + kc * 32);
            acc[t] = __builtin_amdgcn_mfma_f32_16x16x32_f16(af, bf, acc[t], 0, 0, 0);
        }
    }
    int orow0 = row0 + quad * 4;
#pragma unroll
    for (int r = 0; r < 4; ++r) {
        int orow = orow0 + r;
        if (orow < M) {
            float sc = rowscale[orow];
#pragma unroll
            for (int t = 0; t < 8; ++t)
                C[(size_t)orow * 128 + t * 16 + l16] =
                    __half_as_ushort(__float2half_rn(acc[t][r] * sc));
        }
    }
}

__global__ __launch_bounds__(256) void gemm2_mfma(const unsigned short* __restrict__ A,
                                                  const _Float16* __restrict__ Wt,
                                                  const float* __restrict__ rowscale,
                                                  unsigned short* __restrict__ C, int M) {
    int wid = threadIdx.x >> 6, lane = threadIdx.x & 63;
    int quad = lane >> 4, l16 = lane & 15;
    int row0 = blockIdx.x * 64 + wid * 16;
    f32x4 acc[8];
#pragma unroll
    for (int t = 0; t < 8; ++t) acc[t] = (f32x4){0.f, 0.f, 0.f, 0.f};
    int arow = row0 + l16; if (arow >= M) arow = M - 1;
    const _Float16* abase = (const _Float16*)A + (size_t)arow * 128 + quad * 8;
#pragma unroll
    for (int kc = 0; kc < 4; ++kc) {
        f16x8 af = *(const f16x8*)(abase + kc * 32);
#pragma unroll
        for (int t = 0; t < 8; ++t) {
            f16x8 bf = *(const f16x8*)(Wt + (size_t)(t * 16 + l16) * 128 + quad * 8 + kc * 32);
            acc[t] = __builtin_amdgcn_mfma_f32_16x16x32_f16(af, bf, acc[t], 0, 0, 0);
        }
    }
    int orow0 = row0 + quad * 4;
#pragma unroll
    for (int r = 0; r < 4; ++r) {
        int orow = orow0 + r;
        if (orow < M) {
            float sc = rowscale[orow];
#pragma unroll
            for (int t = 0; t < 8; ++t)
                C[(size_t)orow * 128 + t * 16 + l16] =
                    __half_as_ushort(__float2half_rn(acc[t][r] * sc));
        }
    }
}

// ---------------- CSR propagate, 128 f16 feats (layer 1) ----------------
// wave/node; half-wave: 32 lanes x 4 f16 (uint2) per edge, 2 edges/wave-instr;
// 8 edges in flight; packed __hfma2 accumulation.
__global__ __launch_bounds__(256) void prop_kernel(const int* __restrict__ rp,
                                                   const int2* __restrict__ cv,
                                                   const float* __restrict__ dis,
                                                   const unsigned short* __restrict__ t,
                                                   const float* __restrict__ bias,
                                                   unsigned short* __restrict__ out, int n) {
    const long long* cvu = (const long long*)cv;
    int wv = (blockIdx.x * blockDim.x + threadIdx.x) >> 6;
    int lane = threadIdx.x & 63;
    if (wv >= n) return;
    int half = lane >> 5, l5 = lane & 31;
    int beg = rp[wv], end = rp[wv + 1];
    __half2 zh = __float2half2_rn(0.f);
    __half2 acc[4][2];
#pragma unroll
    for (int j = 0; j < 4; ++j) { acc[j][0] = zh; acc[j][1] = zh; }
    int p = beg;
    for (; p + 8 <= end; p += 8) {
        EdgePair q[4];
#pragma unroll
        for (int j = 0; j < 4; ++j) q[j].u = __builtin_nontemporal_load(&cvu[p + 2 * j + half]);
        uint2 tv[4];
#pragma unroll
        for (int j = 0; j < 4; ++j) tv[j] = *(const uint2*)&t[(size_t)q[j].e.s * FEAT + 4 * l5];
#pragma unroll
        for (int j = 0; j < 4; ++j) {
            __half2 ww = __float2half2_rn(q[j].e.w);
            H2U a0, a1; a0.u = tv[j].x; a1.u = tv[j].y;
            acc[j][0] = __hfma2(a0.h2, ww, acc[j][0]);
            acc[j][1] = __hfma2(a1.h2, ww, acc[j][1]);
        }
    }
    for (; p + 2 <= end; p += 2) {
        EdgePair q; q.u = __builtin_nontemporal_load(&cvu[p + half]);
        uint2 tv = *(const uint2*)&t[(size_t)q.e.s * FEAT + 4 * l5];
        __half2 ww = __float2half2_rn(q.e.w);
        H2U a0, a1; a0.u = tv.x; a1.u = tv.y;
        acc[0][0] = __hfma2(a0.h2, ww, acc[0][0]);
        acc[0][1] = __hfma2(a1.h2, ww, acc[0][1]);
    }
    if (p < end) {
        EdgePair q; q.u = __builtin_nontemporal_load(&cvu[p]);
        float wq = half ? 0.f : q.e.w;
        uint2 tv = *(const uint2*)&t[(size_t)q.e.s * FEAT + 4 * l5];
        __half2 ww = __float2half2_rn(wq);
        H2U a0, a1; a0.u = tv.x; a1.u = tv.y;
        acc[1][0] = __hfma2(a0.h2, ww, acc[1][0]);
        acc[1][1] = __hfma2(a1.h2, ww, acc[1][1]);
    }
    float2 s01, s23;
    {
        float2 f0 = __half22float2(acc[0][0]);
        float2 f1 = __half22float2(acc[1][0]);
        float2 f2 = __half22float2(acc[2][0]);
        float2 f3 = __half22float2(acc[3][0]);
        s01.x = (f0.x + f1.x) + (f2.x + f3.x);
        s01.y = (f0.y + f1.y) + (f2.y + f3.y);
        f0 = __half22float2(acc[0][1]);
        f1 = __half22float2(acc[1][1]);
        f2 = __half22float2(acc[2][1]);
        f3 = __half22float2(acc[3][1]);
        s23.x = (f0.x + f1.x) + (f2.x + f3.x);
        s23.y = (f0.y + f1.y) + (f2.y + f3.y);
    }
    s01.x += __shfl_xor(s01.x, 32, 64);
    s01.y += __shfl_xor(s01.y, 32, 64);
    s23.x += __shfl_xor(s23.x, 32, 64);
    s23.y += __shfl_xor(s23.y, 32, 64);
    if (half == 0) {
        float dd = dis[wv];
        float4 b = *(const float4*)&bias[4 * l5];
        float r0 = fmaxf(fmaf(dd, s01.x, b.x), 0.f);
        float r1 = fmaxf(fmaf(dd, s01.y, b.y), 0.f);
        float r2 = fmaxf(fmaf(dd, s23.x, b.z), 0.f);
        float r3 = fmaxf(fmaf(dd, s23.y, b.w), 0.f);
        uint2 pk;
        pk.x = pack2h(r0, r1);
        pk.y = pack2h(r2, r3);
        *(uint2*)&out[(size_t)wv * FEAT + 4 * l5] = pk;
    }
}

// ---------------- layer-2 prop fused with head projection (f16 t) ----------------
// z[i] = dis[i] * (relu(dis[i]*((A+I)@t)[i] + b1) @ Wc)
__global__ __launch_bounds__(256) void prop_zk_kernel(const int* __restrict__ rp,
                                                      const int2* __restrict__ cv,
                                                      const float* __restrict__ dis,
                                                      const unsigned short* __restrict__ t,
                                                      const float* __restrict__ bias,
                                                      const float* __restrict__ Wc,
                                                      float* __restrict__ z, int n) {
    const long long* cvu = (const long long*)cv;
    int wv = (blockIdx.x * blockDim.x + threadIdx.x) >> 6;
    int lane = threadIdx.x & 63;
    if (wv >= n) return;
    int half = lane >> 5, l5 = lane & 31;
    int beg = rp[wv], end = rp[wv + 1];
    __half2 zh = __float2half2_rn(0.f);
    __half2 acc[4][2];
#pragma unroll
    for (int j = 0; j < 4; ++j) { acc[j][0] = zh; acc[j][1] = zh; }
    int p = beg;
    for (; p + 8 <= end; p += 8) {
        EdgePair q[4];
#pragma unroll
        for (int j = 0; j < 4; ++j) q[j].u = __builtin_nontemporal_load(&cvu[p + 2 * j + half]);
        uint2 tv[4];
#pragma unroll
        for (int j = 0; j < 4; ++j) tv[j] = *(const uint2*)&t[(size_t)q[j].e.s * FEAT + 4 * l5];
#pragma unroll
        for (int j = 0; j < 4; ++j) {
            __half2 ww = __float2half2_rn(q[j].e.w);
            H2U a0, a1; a0.u = tv[j].x; a1.u = tv[j].y;
            acc[j][0] = __hfma2(a0.h2, ww, acc[j][0]);
            acc[j][1] = __hfma2(a1.h2, ww, acc[j][1]);
        }
    }
    for (; p + 2 <= end; p += 2) {
        EdgePair q; q.u = __builtin_nontemporal_load(&cvu[p + half]);
        uint2 tv = *(const uint2*)&t[(size_t)q.e.s * FEAT + 4 * l5];
        __half2 ww = __float2half2_rn(q.e.w);
        H2U a0, a1; a0.u = tv.x; a1.u = tv.y;
        acc[0][0] = __hfma2(a0.h2, ww, acc[0][0]);
        acc[0][1] = __hfma2(a1.h2, ww, acc[0][1]);
    }
    if (p < end) {
        EdgePair q; q.u = __builtin_nontemporal_load(&cvu[p]);
        float wq = half ? 0.f : q.e.w;
        uint2 tv = *(const uint2*)&t[(size_t)q.e.s * FEAT + 4 * l5];
        __half2 ww = __float2half2_rn(wq);
        H2U a0, a1; a0.u = tv.x; a1.u = tv.y;
        acc[1][0] = __hfma2(a0.h2, ww, acc[1][0]);
        acc[1][1] = __hfma2(a1.h2, ww, acc[1][1]);
    }
    float2 s01, s23;
    {
        float2 f0 = __half22float2(acc[0][0]);
        float2 f1 = __half22float2(acc[1][0]);
        float2 f2 = __half22float2(acc[2][0]);
        float2 f3 = __half22float2(acc[3][0]);
        s01.x = (f0.x + f1.x) + (f2.x + f3.x);
        s01.y = (f0.y + f1.y) + (f2.y + f3.y);
        f0 = __half22float2(acc[0][1]);
        f1 = __half22float2(acc[1][1]);
        f2 = __half22float2(acc[2][1]);
        f3 = __half22float2(acc[3][1]);
        s23.x = (f0.x + f1.x) + (f2.x + f3.x);
        s23.y = (f0.y + f1.y) + (f2.y + f3.y);
    }
    s01.x += __shfl_xor(s01.x, 32, 64);
    s01.y += __shfl_xor(s01.y, 32, 64);
    s23.x += __shfl_xor(s23.x, 32, 64);
    s23.y += __shfl_xor(s23.y, 32, 64);
    float dd = dis[wv];
    float4 b = *(const float4*)&bias[4 * l5];
    float h0 = fmaxf(fmaf(dd, s01.x, b.x), 0.f);
    float h1 = fmaxf(fmaf(dd, s01.y, b.y), 0.f);
    float h2 = fmaxf(fmaf(dd, s23.x, b.z), 0.f);
    float h3 = fmaxf(fmaf(dd, s23.y, b.w), 0.f);
    float4 w0 = *(const float4*)&Wc[16 * l5];
    float4 w1 = *(const float4*)&Wc[16 * l5 + 4];
    float4 w2 = *(const float4*)&Wc[16 * l5 + 8];
    float4 w3 = *(const float4*)&Wc[16 * l5 + 12];
    float4 par;
    par.x = fmaf(h0, w0.x, fmaf(h1, w1.x, fmaf(h2, w2.x, h3 * w3.x)));
    par.y = fmaf(h0, w0.y, fmaf(h1, w1.y, fmaf(h2, w2.y, h3 * w3.y)));
    par.z = fmaf(h0, w0.z, fmaf(h1, w1.z, fmaf(h2, w2.z, h3 * w3.z)));
    par.w = fmaf(h0, w0.w, fmaf(h1, w1.w, fmaf(h2, w2.w, h3 * w3.w)));
#pragma unroll
    for (int mask = 1; mask < 32; mask <<= 1) {
        par.x += __shfl_xor(par.x, mask, 64);
        par.y += __shfl_xor(par.y, mask, 64);
        par.z += __shfl_xor(par.z, mask, 64);
        par.w += __shfl_xor(par.w, mask, 64);
    }
    if (lane == 0) {
        par.x *= dd; par.y *= dd; par.z *= dd; par.w *= dd;   // outer dis for layer-3 prop
        *(float4*)&z[(size_t)wv * 4] = par;
    }
}

// ---------------- graph segment boundaries (batch is sorted) ----------------
__global__ void gbound_kernel(const int* __restrict__ batch, int* __restrict__ gstart,
                              int n, int G_) {
    int i = blockIdx.x * blockDim.x + threadIdx.x;
    if (i >= n) return;
    int b = batch[i];
    int prev = (i == 0) ? -1 : batch[i - 1];
    for (int g = prev + 1; g <= b; ++g) gstart[g] = i;
    if (i == n - 1) {
        for (int g = b + 1; g <= G_; ++g) gstart[g] = n;
    }
}

// ---------------- combined head weights ----------------
__global__ void wcomb_kernel(const float* __restrict__ W2, const float* __restrict__ Wp,
                             const float* __restrict__ b2, const float* __restrict__ bp,
                             float* Wc, float* bc) {
    int tid = blockIdx.x * blockDim.x + threadIdx.x;
    if (tid < 512) {
        int c = tid >> 2, k = tid & 3;
        float s = 0.f;
        for (int j = 0; j < 200; ++j) s = fmaf(W2[c * 200 + j], Wp[j * 4 + k], s);
        Wc[tid] = s;
    }
    if (tid < 4) {
        float s = bp[tid];
        for (int j = 0; j < 200; ++j) s = fmaf(b2[j], Wp[j * 4 + tid], s);
        bc[tid] = s;
    }
}

// ---------------- CSR propagate, 4 feats: thread/node ----------------
__global__ __launch_bounds__(256) void prop4_kernel(const int* __restrict__ rp,
                                                    const int2* __restrict__ cv,
                                                    const float* __restrict__ dis,
                                                    const float* __restrict__ z,
                                                    float* __restrict__ z2, int n) {
    int i = blockIdx.x * blockDim.x + threadIdx.x;
    if (i >= n) return;
    int beg = rp[i], end = rp[i + 1];
    float4 a0 = {0.f, 0.f, 0.f, 0.f}, a1 = {0.f, 0.f, 0.f, 0.f};
    int p = beg;
    for (; p + 2 <= end; p += 2) {
        EdgePair q0, q1; q0.i2 = cv[p]; q1.i2 = cv[p + 1];
        float4 v0 = *(const float4*)&z[(size_t)q0.e.s * 4];
        float4 v1 = *(const float4*)&z[(size_t)q1.e.s * 4];
        a0.x = fmaf(v0.x, q0.e.w, a0.x); a0.y = fmaf(v0.y, q0.e.w, a0.y);
        a0.z = fmaf(v0.z, q0.e.w, a0.z); a0.w = fmaf(v0.w, q0.e.w, a0.w);
        a1.x = fmaf(v1.x, q1.e.w, a1.x); a1.y = fmaf(v1.y, q1.e.w, a1.y);
        a1.z = fmaf(v1.z, q1.e.w, a1.z); a1.w = fmaf(v1.w, q1.e.w, a1.w);
    }
    if (p < end) {
        EdgePair q; q.i2 = cv[p];
        float4 v = *(const float4*)&z[(size_t)q.e.s * 4];
        a0.x = fmaf(v.x, q.e.w, a0.x); a0.y = fmaf(v.y, q.e.w, a0.y);
        a0.z = fmaf(v.z, q.e.w, a0.z); a0.w = fmaf(v.w, q.e.w, a0.w);
    }
    float dd = dis[i];
    a0.x = dd * (a0.x + a1.x); a0.y = dd * (a0.y + a1.y);
    a0.z = dd * (a0.z + a1.z); a0.w = dd * (a0.w + a1.w);
    *(float4*)&z2[(size_t)i * 4] = a0;
}

// ---------------- segment mean-pool on 4 feats + bias -> out[G x 4] ----------------
__global__ __launch_bounds__(256) void pool4_kernel(const float* __restrict__ z2,
                                                    const int* __restrict__ gstart,
                                                    const float* __restrict__ bc,
                                                    float* __restrict__ out, int G_) {
    __shared__ float sd[256];
    int g = blockIdx.x;
    int k = threadIdx.x & 3;
    int sub = threadIdx.x >> 2;
    int beg = gstart[g], end = gstart[g + 1];
    float s = 0.f;
    for (int i = beg + sub; i < end; i += 64) s += z2[(size_t)i * 4 + k];
    sd[threadIdx.x] = s;
    __syncthreads();
    for (int off = 32; off > 0; off >>= 1) {
        if (sub < off) sd[threadIdx.x] += sd[threadIdx.x + off * 4];
        __syncthreads();
    }
    if (sub == 0) {
        int c = end - beg;
        out[g * 4 + k] = sd[k] / (float)max(c, 1) + bc[k];
    }
}

extern "C" void kernel_launch(void* const* d_in, const int* in_sizes, int n_in,
                              void* d_out, int out_size, void* d_ws, size_t ws_size,
                              hipStream_t stream) {
    const float* x    = (const float*)d_in[0];
    const int*   ei   = (const int*)d_in[1];
    const float* eatt = (const float*)d_in[2];
    const int*   batch= (const int*)d_in[3];
    const float* W0   = (const float*)d_in[4];
    const float* b0   = (const float*)d_in[5];
    const float* W1   = (const float*)d_in[6];
    const float* b1   = (const float*)d_in[7];
    const float* W2   = (const float*)d_in[8];
    const float* b2   = (const float*)d_in[9];
    const float* Wp   = (const float*)d_in[10];
    const float* bp   = (const float*)d_in[11];
    float* out = (float*)d_out;

    const int Nn = in_sizes[0] / FEAT;        // 100000
    const int E_ = in_sizes[2];               // 1600000
    const int G_ = out_size / 4;              // 500
    const int NNZ = E_ + Nn;
    const int NB = ((Nn - 1) >> BSH) + 1;     // 391 buckets

    const int* e_src = ei;
    const int* e_dst = ei + E_;

    // ---- workspace layout ----
    char* ws = (char*)d_ws;
    size_t off = 0;
    auto alloc = [&](size_t bytes) { void* p = ws + off; off = (off + bytes + 255) & ~(size_t)255; return p; };
    float* dis     = (float*)alloc((size_t)Nn * 4);
    int*   cnt     = (int*)  alloc((size_t)Nn * 4);
    int*   rp      = (int*)  alloc((size_t)(Nn + 1) * 4);
    int*   bsum    = (int*)  alloc(1024 * 4);
    int*   gcnt    = (int*)  alloc((size_t)NB * 4);
    int2*  cv      = (int2*) alloc((size_t)NNZ * 8);
    unsigned short* bufA = (unsigned short*)alloc((size_t)NB * BCAP * 8);  // h1 f16; aliases bins (25.6 MB)
    unsigned short* bufB = (unsigned short*)alloc((size_t)Nn * FEAT * 2);  // t1/t2 f16
    int*   gstart  = (int*)  alloc((size_t)(G_ + 1) * 4);
    float* z       = (float*)alloc((size_t)Nn * 4 * 4);
    float* z2      = (float*)alloc((size_t)Nn * 4 * 4);
    float* Wc      = (float*)alloc(512 * 4);
    float* bc      = (float*)alloc(4 * 4);
    _Float16* Wt0  = (_Float16*)alloc(128 * 128 * 2);
    _Float16* Wt1  = (_Float16*)alloc(128 * 128 * 2);
    int2*  bins    = (int2*)bufA;   // dead before prop1 writes bufA
    (void)ws_size;

    const int T = 256;
    auto cdiv = [](int a, int b) { return (a + b - 1) / b; };

    // small independent preps
    wcomb_kernel<<<2, T, 0, stream>>>(W2, Wp, b2, bp, Wc, bc);
    gbound_kernel<<<cdiv(Nn, T), T, 0, stream>>>(batch, gstart, Nn, G_);
    wprep_kernel<<<64, T, 0, stream>>>(W0, Wt0);
    wprep_kernel<<<64, T, 0, stream>>>(W1, Wt1);

    // CSR build via multisplit (+ fused deg->dis in scat2)
    (void)hipMemsetAsync(gcnt, 0, (size_t)NB * 4, stream);
    bin1_kernel<<<cdiv(E_, 4096), T, 0, stream>>>(e_src, e_dst, eatt, gcnt, bins, E_, NB);
    cnt2_kernel<<<NB, T, 0, stream>>>(bins, gcnt, cnt, Nn);
    int nb = cdiv(Nn, 1024);
    scan_blk<<<nb, T, 0, stream>>>(cnt, rp, bsum, Nn);
    scan_top<<<1, T, 0, stream>>>(bsum, nb);
    scan_add<<<cdiv(Nn, T), T, 0, stream>>>(rp, bsum, Nn, NNZ);
    scat2_kernel<<<NB, T, 0, stream>>>(bins, gcnt, rp, cv, dis, Nn);

    // layer 1: bufB = f16(dis .* (x@W0)) via MFMA; bufA = f16(relu(dis .* ((A+I)@bufB) + b0))
    gemm1_mfma<<<cdiv(Nn, 64), T, 0, stream>>>(x, Wt0, dis, bufB, Nn);
    prop_kernel<<<cdiv(Nn * 64, T), T, 0, stream>>>(rp, cv, dis, bufB, b0, bufA, Nn);

    // layer 2 + head projection fused: bufB = f16(dis .* (bufA@W1)) via MFMA; z = dis .* (relu(...)@Wc)
    gemm2_mfma<<<cdiv(Nn, 64), T, 0, stream>>>(bufA, Wt1, dis, bufB, Nn);
    prop_zk_kernel<<<cdiv(Nn * 64, T), T, 0, stream>>>(rp, cv, dis, bufB, b1, Wc, z, Nn);

    // layer 3 + pool
    prop4_kernel<<<cdiv(Nn, T), T, 0, stream>>>(rp, cv, dis, z, z2, Nn);
    pool4_kernel<<<G_, T, 0, stream>>>(z2, gstart, bc, out, G_);
}

// Round 12
// 427.398 us; speedup vs baseline: 1.1574x; 1.0085x over previous
//
#include <hip/hip_runtime.h>
#include <hip/hip_bf16.h>
#include <hip/hip_fp16.h>

// GCN, dis-folded: A_norm = D^-1/2 (A_w + I) D^-1/2; CSR stores raw w.
// R12: CSR build collapsed: bin1 -> bbase (1 block) -> buildcsr (histogram+scan+
//      scatter+dis in one kernel/bucket). Tiny preps merged into one dispatch.
//      Props/GEMMs unchanged from R11 (props fabric-floored at 8 XCD x WS).

#define FEAT 128
#define BSH 8                 // bucket shift
#define BCAP 8192             // entries per bucket (mean 4092)

typedef union { int2 i2; long long u; struct { int s; float w; } e; } EdgePair;
typedef union { unsigned u; __half2 h2; } H2U;
typedef _Float16 f16x8 __attribute__((ext_vector_type(8)));
typedef float f32x4 __attribute__((ext_vector_type(4)));

__device__ __forceinline__ unsigned pack2h(float a, float b) {
    return (unsigned)__half_as_ushort(__float2half_rn(a)) |
           ((unsigned)__half_as_ushort(__float2half_rn(b)) << 16);   // RNE both
}

// ---------------- pass 1: bin edges by dst>>8 ----------------
__global__ __launch_bounds__(256) void bin1_kernel(const int* __restrict__ src,
                                                   const int* __restrict__ dst,
                                                   const float* __restrict__ w,
                                                   int* __restrict__ gcnt,
                                                   int2* __restrict__ bins,
                                                   int E_, int NB) {
    __shared__ int lh[392], lbase[392], lcur[392];
    const int CHUNK = 4096;
    int base = blockIdx.x * CHUNK;
    for (int t = threadIdx.x; t < NB; t += 256) { lh[t] = 0; lcur[t] = 0; }
    __syncthreads();
    int ds[16];
#pragma unroll
    for (int j = 0; j < 16; ++j) {
        int e = base + j * 256 + threadIdx.x;
        ds[j] = (e < E_) ? dst[e] : -1;
        if (ds[j] >= 0) atomicAdd(&lh[ds[j] >> BSH], 1);
    }
    __syncthreads();
    for (int t = threadIdx.x; t < NB; t += 256)
        if (lh[t] > 0) lbase[t] = atomicAdd(&gcnt[t], lh[t]);
    __syncthreads();
#pragma unroll
    for (int j = 0; j < 16; ++j) {
        int e = base + j * 256 + threadIdx.x;
        if (ds[j] >= 0) {
            int b = ds[j] >> BSH;
            int idx = lbase[b] + atomicAdd(&lcur[b], 1);
            if (idx < BCAP) {
                EdgePair p;
                p.e.s = src[e] | ((ds[j] & 255) << 20);
                p.e.w = w[e];
                bins[(size_t)b * BCAP + idx] = p.i2;
            }
        }
    }
}

// ---------------- bucket bases: exclusive scan of (gcnt[b] + nvalid(b)) ----------------
__global__ __launch_bounds__(256) void bbase_kernel(const int* __restrict__ gcnt,
                                                    int* __restrict__ bbase,
                                                    int* __restrict__ rp,
                                                    int NB, int n) {
    __shared__ int sd[512];
    int tid = threadIdx.x;
    for (int i = tid; i < NB; i += 256) {
        int nvalid = min(256, n - (i << BSH));
        sd[i] = min(gcnt[i], BCAP) + nvalid;
    }
    __syncthreads();
    if (tid == 0) {
        int run = 0;
        for (int i = 0; i < NB; ++i) { int v = sd[i]; sd[i] = run; run += v; }
        rp[n] = run;
    }
    __syncthreads();
    for (int i = tid; i < NB; i += 256) bbase[i] = sd[i];
}

// ---------------- fused CSR build: histogram + local scan + rp/dis + scatter ----------------
__global__ __launch_bounds__(256) void buildcsr_kernel(const int2* __restrict__ bins,
                                                       const int* __restrict__ gcnt,
                                                       const int* __restrict__ bbase,
                                                       int* __restrict__ rp,
                                                       float* __restrict__ dis,
                                                       int2* __restrict__ cv, int n) {
    __shared__ int lh[256];
    __shared__ float wsum[256];
    __shared__ int sc[256];
    __shared__ int lcur[256];
    int b = blockIdx.x;
    int node0 = b << BSH;
    int node = node0 + threadIdx.x;
    bool valid = node < n;
    lh[threadIdx.x] = 0;
    wsum[threadIdx.x] = 1.0f;   // self-loop weight
    __syncthreads();
    int m = min(gcnt[b], BCAP);
    const int2* bp = bins + (size_t)b * BCAP;
    for (int i = threadIdx.x; i < m; i += 256) {
        int2 raw = bp[i];
        unsigned pk = (unsigned)raw.x;
        int dlo = pk >> 20;
        atomicAdd(&lh[dlo], 1);
        atomicAdd(&wsum[dlo], __int_as_float(raw.y));
    }
    __syncthreads();
    int cnt_t = valid ? (lh[threadIdx.x] + 1) : 0;   // +1 self-loop
    sc[threadIdx.x] = cnt_t;
    __syncthreads();
    for (int off = 1; off < 256; off <<= 1) {
        int x = (threadIdx.x >= off) ? sc[threadIdx.x - off] : 0;
        __syncthreads();
        sc[threadIdx.x] += x;
        __syncthreads();
    }
    int excl = sc[threadIdx.x] - cnt_t;
    int base = bbase[b];
    if (valid) {
        rp[node] = base + excl;
        dis[node] = rsqrtf(fmaxf(wsum[threadIdx.x], 1e-12f));
    }
    lcur[threadIdx.x] = base + excl;
    __syncthreads();
    for (int i = threadIdx.x; i < m; i += 256) {
        int2 raw = bp[i];                       // second read: L2-hot
        unsigned pk = (unsigned)raw.x;
        int dlo = pk >> 20;
        int pos = atomicAdd(&lcur[dlo], 1);
        EdgePair q; q.e.s = (int)(pk & 0xFFFFF); q.i2.y = raw.y;
        cv[pos] = q.i2;
    }
    __syncthreads();
    if (valid) {                                // self-loop entry, w = 1
        int pos = atomicAdd(&lcur[threadIdx.x], 1);
        EdgePair q; q.e.s = node; q.e.w = 1.0f;
        cv[pos] = q.i2;
    }
}

// ---------------- merged tiny preps ----------------
// blocks [0,64): Wt0; [64,128): Wt1; 128: Wc+bc; [129, 129+nbg): gbound
__global__ __launch_bounds__(256) void prep_kernel(const float* __restrict__ W0,
                                                   const float* __restrict__ W1,
                                                   const float* __restrict__ W2,
                                                   const float* __restrict__ Wp,
                                                   const float* __restrict__ b2,
                                                   const float* __restrict__ bp,
                                                   const int* __restrict__ batch,
                                                   _Float16* __restrict__ Wt0,
                                                   _Float16* __restrict__ Wt1,
                                                   float* __restrict__ Wc,
                                                   float* __restrict__ bc,
                                                   int* __restrict__ gstart,
                                                   int n, int G_) {
    int blk = blockIdx.x;
    if (blk < 64) {
        int tid = blk * 256 + threadIdx.x;
        int nn = tid >> 7, k = tid & 127;
        Wt0[nn * 128 + k] = (_Float16)W0[k * 128 + nn];
    } else if (blk < 128) {
        int tid = (blk - 64) * 256 + threadIdx.x;
        int nn = tid >> 7, k = tid & 127;
        Wt1[nn * 128 + k] = (_Float16)W1[k * 128 + nn];
    } else if (blk == 128) {
        for (int tid = threadIdx.x; tid < 512; tid += 256) {
            int c = tid >> 2, k = tid & 3;
            float s = 0.f;
            for (int j = 0; j < 200; ++j) s = fmaf(W2[c * 200 + j], Wp[j * 4 + k], s);
            Wc[tid] = s;
        }
        if (threadIdx.x < 4) {
            float s = bp[threadIdx.x];
            for (int j = 0; j < 200; ++j) s = fmaf(b2[j], Wp[j * 4 + threadIdx.x], s);
            bc[threadIdx.x] = s;
        }
    } else {
        int i = (blk - 129) * 256 + threadIdx.x;
        if (i >= n) return;
        int b = batch[i];
        int prev = (i == 0) ? -1 : batch[i - 1];
        for (int g = prev + 1; g <= b; ++g) gstart[g] = i;
        if (i == n - 1) {
            for (int g = b + 1; g <= G_; ++g) gstart[g] = n;
        }
    }
}

// ---------------- MFMA GEMM: C_f16[M x 128] = rowscale .* (A @ W), Wt[n][k] f16 ----------------
__global__ __launch_bounds__(256) void gemm1_mfma(const float* __restrict__ A,
                                                  const _Float16* __restrict__ Wt,
                                                  const float* __restrict__ rowscale,
                                                  unsigned short* __restrict__ C, int M) {
    int wid = threadIdx.x >> 6, lane = threadIdx.x & 63;
    int quad = lane >> 4, l16 = lane & 15;
    int row0 = blockIdx.x * 64 + wid * 16;
    f32x4 acc[8];
#pragma unroll
    for (int t = 0; t < 8; ++t) acc[t] = (f32x4){0.f, 0.f, 0.f, 0.f};
    int arow = row0 + l16; if (arow >= M) arow = M - 1;   // clamp: pollutes only discarded D rows
    const float* abase = A + (size_t)arow * 128 + quad * 8;
#pragma unroll
    for (int kc = 0; kc < 4; ++kc) {
        float4 a0 = *(const float4*)(abase + kc * 32);
        float4 a1 = *(const float4*)(abase + kc * 32 + 4);
        f16x8 af = { (_Float16)a0.x, (_Float16)a0.y, (_Float16)a0.z, (_Float16)a0.w,
                     (_Float16)a1.x, (_Float16)a1.y, (_Float16)a1.z, (_Float16)a1.w };
#pragma unroll
        for (int t = 0; t < 8; ++t) {
            f16x8 bf = *(const f16x8*)(Wt + (size_t)(t * 16 + l16) * 128 + quad * 8 + kc * 32);
            acc[t] = __builtin_amdgcn_mfma_f32_16x16x32_f16(af, bf, acc[t], 0, 0, 0);
        }
    }
    int orow0 = row0 + quad * 4;
#pragma unroll
    for (int r = 0; r < 4; ++r) {
        int orow = orow0 + r;
        if (orow < M) {
            float sc = rowscale[orow];
#pragma unroll
            for (int t = 0; t < 8; ++t)
                C[(size_t)orow * 128 + t * 16 + l16] =
                    __half_as_ushort(__float2half_rn(acc[t][r] * sc));
        }
    }
}

__global__ __launch_bounds__(256) void gemm2_mfma(const unsigned short* __restrict__ A,
                                                  const _Float16* __restrict__ Wt,
                                                  const float* __restrict__ rowscale,
                                                  unsigned short* __restrict__ C, int M) {
    int wid = threadIdx.x >> 6, lane = threadIdx.x & 63;
    int quad = lane >> 4, l16 = lane & 15;
    int row0 = blockIdx.x * 64 + wid * 16;
    f32x4 acc[8];
#pragma unroll
    for (int t = 0; t < 8; ++t) acc[t] = (f32x4){0.f, 0.f, 0.f, 0.f};
    int arow = row0 + l16; if (arow >= M) arow = M - 1;
    const _Float16* abase = (const _Float16*)A + (size_t)arow * 128 + quad * 8;
#pragma unroll
    for (int kc = 0; kc < 4; ++kc) {
        f16x8 af = *(const f16x8*)(abase + kc * 32);
#pragma unroll
        for (int t = 0; t < 8; ++t) {
            f16x8 bf = *(const f16x8*)(Wt + (size_t)(t * 16 + l16) * 128 + quad * 8 + kc * 32);
            acc[t] = __builtin_amdgcn_mfma_f32_16x16x32_f16(af, bf, acc[t], 0, 0, 0);
        }
    }
    int orow0 = row0 + quad * 4;
#pragma unroll
    for (int r = 0; r < 4; ++r) {
        int orow = orow0 + r;
        if (orow < M) {
            float sc = rowscale[orow];
#pragma unroll
            for (int t = 0; t < 8; ++t)
                C[(size_t)orow * 128 + t * 16 + l16] =
                    __half_as_ushort(__float2half_rn(acc[t][r] * sc));
        }
    }
}

// ---------------- CSR propagate, 128 f16 feats (layer 1) ----------------
// wave/node; half-wave: 32 lanes x 4 f16 (uint2) per edge, 2 edges/wave-instr;
// 8 edges in flight; packed __hfma2 accumulation.
__global__ __launch_bounds__(256) void prop_kernel(const int* __restrict__ rp,
                                                   const int2* __restrict__ cv,
                                                   const float* __restrict__ dis,
                                                   const unsigned short* __restrict__ t,
                                                   const float* __restrict__ bias,
                                                   unsigned short* __restrict__ out, int n) {
    const long long* cvu = (const long long*)cv;
    int wv = (blockIdx.x * blockDim.x + threadIdx.x) >> 6;
    int lane = threadIdx.x & 63;
    if (wv >= n) return;
    int half = lane >> 5, l5 = lane & 31;
    int beg = rp[wv], end = rp[wv + 1];
    __half2 zh = __float2half2_rn(0.f);
    __half2 acc[4][2];
#pragma unroll
    for (int j = 0; j < 4; ++j) { acc[j][0] = zh; acc[j][1] = zh; }
    int p = beg;
    for (; p + 8 <= end; p += 8) {
        EdgePair q[4];
#pragma unroll
        for (int j = 0; j < 4; ++j) q[j].u = __builtin_nontemporal_load(&cvu[p + 2 * j + half]);
        uint2 tv[4];
#pragma unroll
        for (int j = 0; j < 4; ++j) tv[j] = *(const uint2*)&t[(size_t)q[j].e.s * FEAT + 4 * l5];
#pragma unroll
        for (int j = 0; j < 4; ++j) {
            __half2 ww = __float2half2_rn(q[j].e.w);
            H2U a0, a1; a0.u = tv[j].x; a1.u = tv[j].y;
            acc[j][0] = __hfma2(a0.h2, ww, acc[j][0]);
            acc[j][1] = __hfma2(a1.h2, ww, acc[j][1]);
        }
    }
    for (; p + 2 <= end; p += 2) {
        EdgePair q; q.u = __builtin_nontemporal_load(&cvu[p + half]);
        uint2 tv = *(const uint2*)&t[(size_t)q.e.s * FEAT + 4 * l5];
        __half2 ww = __float2half2_rn(q.e.w);
        H2U a0, a1; a0.u = tv.x; a1.u = tv.y;
        acc[0][0] = __hfma2(a0.h2, ww, acc[0][0]);
        acc[0][1] = __hfma2(a1.h2, ww, acc[0][1]);
    }
    if (p < end) {
        EdgePair q; q.u = __builtin_nontemporal_load(&cvu[p]);
        float wq = half ? 0.f : q.e.w;
        uint2 tv = *(const uint2*)&t[(size_t)q.e.s * FEAT + 4 * l5];
        __half2 ww = __float2half2_rn(wq);
        H2U a0, a1; a0.u = tv.x; a1.u = tv.y;
        acc[1][0] = __hfma2(a0.h2, ww, acc[1][0]);
        acc[1][1] = __hfma2(a1.h2, ww, acc[1][1]);
    }
    float2 s01, s23;
    {
        float2 f0 = __half22float2(acc[0][0]);
        float2 f1 = __half22float2(acc[1][0]);
        float2 f2 = __half22float2(acc[2][0]);
        float2 f3 = __half22float2(acc[3][0]);
        s01.x = (f0.x + f1.x) + (f2.x + f3.x);
        s01.y = (f0.y + f1.y) + (f2.y + f3.y);
        f0 = __half22float2(acc[0][1]);
        f1 = __half22float2(acc[1][1]);
        f2 = __half22float2(acc[2][1]);
        f3 = __half22float2(acc[3][1]);
        s23.x = (f0.x + f1.x) + (f2.x + f3.x);
        s23.y = (f0.y + f1.y) + (f2.y + f3.y);
    }
    s01.x += __shfl_xor(s01.x, 32, 64);
    s01.y += __shfl_xor(s01.y, 32, 64);
    s23.x += __shfl_xor(s23.x, 32, 64);
    s23.y += __shfl_xor(s23.y, 32, 64);
    if (half == 0) {
        float dd = dis[wv];
        float4 b = *(const float4*)&bias[4 * l5];
        float r0 = fmaxf(fmaf(dd, s01.x, b.x), 0.f);
        float r1 = fmaxf(fmaf(dd, s01.y, b.y), 0.f);
        float r2 = fmaxf(fmaf(dd, s23.x, b.z), 0.f);
        float r3 = fmaxf(fmaf(dd, s23.y, b.w), 0.f);
        uint2 pk;
        pk.x = pack2h(r0, r1);
        pk.y = pack2h(r2, r3);
        *(uint2*)&out[(size_t)wv * FEAT + 4 * l5] = pk;
    }
}

// ---------------- layer-2 prop fused with head projection (f16 t) ----------------
// z[i] = dis[i] * (relu(dis[i]*((A+I)@t)[i] + b1) @ Wc)
__global__ __launch_bounds__(256) void prop_zk_kernel(const int* __restrict__ rp,
                                                      const int2* __restrict__ cv,
                                                      const float* __restrict__ dis,
                                                      const unsigned short* __restrict__ t,
                                                      const float* __restrict__ bias,
                                                      const float* __restrict__ Wc,
                                                      float* __restrict__ z, int n) {
    const long long* cvu = (const long long*)cv;
    int wv = (blockIdx.x * blockDim.x + threadIdx.x) >> 6;
    int lane = threadIdx.x & 63;
    if (wv >= n) return;
    int half = lane >> 5, l5 = lane & 31;
    int beg = rp[wv], end = rp[wv + 1];
    __half2 zh = __float2half2_rn(0.f);
    __half2 acc[4][2];
#pragma unroll
    for (int j = 0; j < 4; ++j) { acc[j][0] = zh; acc[j][1] = zh; }
    int p = beg;
    for (; p + 8 <= end; p += 8) {
        EdgePair q[4];
#pragma unroll
        for (int j = 0; j < 4; ++j) q[j].u = __builtin_nontemporal_load(&cvu[p + 2 * j + half]);
        uint2 tv[4];
#pragma unroll
        for (int j = 0; j < 4; ++j) tv[j] = *(const uint2*)&t[(size_t)q[j].e.s * FEAT + 4 * l5];
#pragma unroll
        for (int j = 0; j < 4; ++j) {
            __half2 ww = __float2half2_rn(q[j].e.w);
            H2U a0, a1; a0.u = tv[j].x; a1.u = tv[j].y;
            acc[j][0] = __hfma2(a0.h2, ww, acc[j][0]);
            acc[j][1] = __hfma2(a1.h2, ww, acc[j][1]);
        }
    }
    for (; p + 2 <= end; p += 2) {
        EdgePair q; q.u = __builtin_nontemporal_load(&cvu[p + half]);
        uint2 tv = *(const uint2*)&t[(size_t)q.e.s * FEAT + 4 * l5];
        __half2 ww = __float2half2_rn(q.e.w);
        H2U a0, a1; a0.u = tv.x; a1.u = tv.y;
        acc[0][0] = __hfma2(a0.h2, ww, acc[0][0]);
        acc[0][1] = __hfma2(a1.h2, ww, acc[0][1]);
    }
    if (p < end) {
        EdgePair q; q.u = __builtin_nontemporal_load(&cvu[p]);
        float wq = half ? 0.f : q.e.w;
        uint2 tv = *(const uint2*)&t[(size_t)q.e.s * FEAT + 4 * l5];
        __half2 ww = __float2half2_rn(wq);
        H2U a0, a1; a0.u = tv.x; a1.u = tv.y;
        acc[1][0] = __hfma2(a0.h2, ww, acc[1][0]);
        acc[1][1] = __hfma2(a1.h2, ww, acc[1][1]);
    }
    float2 s01, s23;
    {
        float2 f0 = __half22float2(acc[0][0]);
        float2 f1 = __half22float2(acc[1][0]);
        float2 f2 = __half22float2(acc[2][0]);
        float2 f3 = __half22float2(acc[3][0]);
        s01.x = (f0.x + f1.x) + (f2.x + f3.x);
        s01.y = (f0.y + f1.y) + (f2.y + f3.y);
        f0 = __half22float2(acc[0][1]);
        f1 = __half22float2(acc[1][1]);
        f2 = __half22float2(acc[2][1]);
        f3 = __half22float2(acc[3][1]);
        s23.x = (f0.x + f1.x) + (f2.x + f3.x);
        s23.y = (f0.y + f1.y) + (f2.y + f3.y);
    }
    s01.x += __shfl_xor(s01.x, 32, 64);
    s01.y += __shfl_xor(s01.y, 32, 64);
    s23.x += __shfl_xor(s23.x, 32, 64);
    s23.y += __shfl_xor(s23.y, 32, 64);
    float dd = dis[wv];
    float4 b = *(const float4*)&bias[4 * l5];
    float h0 = fmaxf(fmaf(dd, s01.x, b.x), 0.f);
    float h1 = fmaxf(fmaf(dd, s01.y, b.y), 0.f);
    float h2 = fmaxf(fmaf(dd, s23.x, b.z), 0.f);
    float h3 = fmaxf(fmaf(dd, s23.y, b.w), 0.f);
    float4 w0 = *(const float4*)&Wc[16 * l5];
    float4 w1 = *(const float4*)&Wc[16 * l5 + 4];
    float4 w2 = *(const float4*)&Wc[16 * l5 + 8];
    float4 w3 = *(const float4*)&Wc[16 * l5 + 12];
    float4 par;
    par.x = fmaf(h0, w0.x, fmaf(h1, w1.x, fmaf(h2, w2.x, h3 * w3.x)));
    par.y = fmaf(h0, w0.y, fmaf(h1, w1.y, fmaf(h2, w2.y, h3 * w3.y)));
    par.z = fmaf(h0, w0.z, fmaf(h1, w1.z, fmaf(h2, w2.z, h3 * w3.z)));
    par.w = fmaf(h0, w0.w, fmaf(h1, w1.w, fmaf(h2, w2.w, h3 * w3.w)));
#pragma unroll
    for (int mask = 1; mask < 32; mask <<= 1) {
        par.x += __shfl_xor(par.x, mask, 64);
        par.y += __shfl_xor(par.y, mask, 64);
        par.z += __shfl_xor(par.z, mask, 64);
        par.w += __shfl_xor(par.w, mask, 64);
    }
    if (lane == 0) {
        par.x *= dd; par.y *= dd; par.z *= dd; par.w *= dd;   // outer dis for layer-3 prop
        *(float4*)&z[(size_t)wv * 4] = par;
    }
}

// ---------------- CSR propagate, 4 feats: thread/node ----------------
__global__ __launch_bounds__(256) void prop4_kernel(const int* __restrict__ rp,
                                                    const int2* __restrict__ cv,
                                                    const float* __restrict__ dis,
                                                    const float* __restrict__ z,
                                                    float* __restrict__ z2, int n) {
    int i = blockIdx.x * blockDim.x + threadIdx.x;
    if (i >= n) return;
    int beg = rp[i], end = rp[i + 1];
    float4 a0 = {0.f, 0.f, 0.f, 0.f}, a1 = {0.f, 0.f, 0.f, 0.f};
    int p = beg;
    for (; p + 2 <= end; p += 2) {
        EdgePair q0, q1; q0.i2 = cv[p]; q1.i2 = cv[p + 1];
        float4 v0 = *(const float4*)&z[(size_t)q0.e.s * 4];
        float4 v1 = *(const float4*)&z[(size_t)q1.e.s * 4];
        a0.x = fmaf(v0.x, q0.e.w, a0.x); a0.y = fmaf(v0.y, q0.e.w, a0.y);
        a0.z = fmaf(v0.z, q0.e.w, a0.z); a0.w = fmaf(v0.w, q0.e.w, a0.w);
        a1.x = fmaf(v1.x, q1.e.w, a1.x); a1.y = fmaf(v1.y, q1.e.w, a1.y);
        a1.z = fmaf(v1.z, q1.e.w, a1.z); a1.w = fmaf(v1.w, q1.e.w, a1.w);
    }
    if (p < end) {
        EdgePair q; q.i2 = cv[p];
        float4 v = *(const float4*)&z[(size_t)q.e.s * 4];
        a0.x = fmaf(v.x, q.e.w, a0.x); a0.y = fmaf(v.y, q.e.w, a0.y);
        a0.z = fmaf(v.z, q.e.w, a0.z); a0.w = fmaf(v.w, q.e.w, a0.w);
    }
    float dd = dis[i];
    a0.x = dd * (a0.x + a1.x); a0.y = dd * (a0.y + a1.y);
    a0.z = dd * (a0.z + a1.z); a0.w = dd * (a0.w + a1.w);
    *(float4*)&z2[(size_t)i * 4] = a0;
}

// ---------------- segment mean-pool on 4 feats + bias -> out[G x 4] ----------------
__global__ __launch_bounds__(256) void pool4_kernel(const float* __restrict__ z2,
                                                    const int* __restrict__ gstart,
                                                    const float* __restrict__ bc,
                                                    float* __restrict__ out, int G_) {
    __shared__ float sd[256];
    int g = blockIdx.x;
    int k = threadIdx.x & 3;
    int sub = threadIdx.x >> 2;
    int beg = gstart[g], end = gstart[g + 1];
    float s = 0.f;
    for (int i = beg + sub; i < end; i += 64) s += z2[(size_t)i * 4 + k];
    sd[threadIdx.x] = s;
    __syncthreads();
    for (int off = 32; off > 0; off >>= 1) {
        if (sub < off) sd[threadIdx.x] += sd[threadIdx.x + off * 4];
        __syncthreads();
    }
    if (sub == 0) {
        int c = end - beg;
        out[g * 4 + k] = sd[k] / (float)max(c, 1) + bc[k];
    }
}

extern "C" void kernel_launch(void* const* d_in, const int* in_sizes, int n_in,
                              void* d_out, int out_size, void* d_ws, size_t ws_size,
                              hipStream_t stream) {
    const float* x    = (const float*)d_in[0];
    const int*   ei   = (const int*)d_in[1];
    const float* eatt = (const float*)d_in[2];
    const int*   batch= (const int*)d_in[3];
    const float* W0   = (const float*)d_in[4];
    const float* b0   = (const float*)d_in[5];
    const float* W1   = (const float*)d_in[6];
    const float* b1   = (const float*)d_in[7];
    const float* W2   = (const float*)d_in[8];
    const float* b2   = (const float*)d_in[9];
    const float* Wp   = (const float*)d_in[10];
    const float* bp   = (const float*)d_in[11];
    float* out = (float*)d_out;

    const int Nn = in_sizes[0] / FEAT;        // 100000
    const int E_ = in_sizes[2];               // 1600000
    const int G_ = out_size / 4;              // 500
    const int NNZ = E_ + Nn;
    const int NB = ((Nn - 1) >> BSH) + 1;     // 391 buckets

    const int* e_src = ei;
    const int* e_dst = ei + E_;

    // ---- workspace layout ----
    char* ws = (char*)d_ws;
    size_t off = 0;
    auto alloc = [&](size_t bytes) { void* p = ws + off; off = (off + bytes + 255) & ~(size_t)255; return p; };
    float* dis     = (float*)alloc((size_t)Nn * 4);
    int*   rp      = (int*)  alloc((size_t)(Nn + 1) * 4);
    int*   gcnt    = (int*)  alloc((size_t)NB * 4);
    int*   bbase   = (int*)  alloc((size_t)NB * 4);
    int2*  cv      = (int2*) alloc((size_t)NNZ * 8);
    unsigned short* bufA = (unsigned short*)alloc((size_t)NB * BCAP * 8);  // h1 f16; aliases bins (25.6 MB)
    unsigned short* bufB = (unsigned short*)alloc((size_t)Nn * FEAT * 2);  // t1/t2 f16
    int*   gstart  = (int*)  alloc((size_t)(G_ + 1) * 4);
    float* z       = (float*)alloc((size_t)Nn * 4 * 4);
    float* z2      = (float*)alloc((size_t)Nn * 4 * 4);
    float* Wc      = (float*)alloc(512 * 4);
    float* bc      = (float*)alloc(4 * 4);
    _Float16* Wt0  = (_Float16*)alloc(128 * 128 * 2);
    _Float16* Wt1  = (_Float16*)alloc(128 * 128 * 2);
    int2*  bins    = (int2*)bufA;   // dead before prop1 writes bufA
    (void)ws_size;

    const int T = 256;
    auto cdiv = [](int a, int b) { return (a + b - 1) / b; };

    // merged tiny preps (Wt0, Wt1, Wc/bc, gstart)
    prep_kernel<<<129 + cdiv(Nn, T), T, 0, stream>>>(W0, W1, W2, Wp, b2, bp, batch,
                                                     Wt0, Wt1, Wc, bc, gstart, Nn, G_);

    // CSR build: bin -> bbase scan -> fused histogram/scan/scatter (+dis)
    (void)hipMemsetAsync(gcnt, 0, (size_t)NB * 4, stream);
    bin1_kernel<<<cdiv(E_, 4096), T, 0, stream>>>(e_src, e_dst, eatt, gcnt, bins, E_, NB);
    bbase_kernel<<<1, T, 0, stream>>>(gcnt, bbase, rp, NB, Nn);
    buildcsr_kernel<<<NB, T, 0, stream>>>(bins, gcnt, bbase, rp, dis, cv, Nn);

    // layer 1: bufB = f16(dis .* (x@W0)) via MFMA; bufA = f16(relu(dis .* ((A+I)@bufB) + b0))
    gemm1_mfma<<<cdiv(Nn, 64), T, 0, stream>>>(x, Wt0, dis, bufB, Nn);
    prop_kernel<<<cdiv(Nn * 64, T), T, 0, stream>>>(rp, cv, dis, bufB, b0, bufA, Nn);

    // layer 2 + head projection fused: bufB = f16(dis .* (bufA@W1)) via MFMA; z = dis .* (relu(...)@Wc)
    gemm2_mfma<<<cdiv(Nn, 64), T, 0, stream>>>(bufA, Wt1, dis, bufB, Nn);
    prop_zk_kernel<<<cdiv(Nn * 64, T), T, 0, stream>>>(rp, cv, dis, bufB, b1, Wc, z, Nn);

    // layer 3 + pool
    prop4_kernel<<<cdiv(Nn, T), T, 0, stream>>>(rp, cv, dis, z, z2, Nn);
    pool4_kernel<<<G_, T, 0, stream>>>(z2, gstart, bc, out, G_);
}